// Round 9
// baseline (1285.015 us; speedup 1.0000x reference)
//
#include <hip/hip_runtime.h>
#include <hip/hip_bf16.h>

// Problem constants (Network_29197187678952)
#define NN 50000          // nodes
#define NE 1600000        // edges
#define NB 8              // batch
#define NT 80             // timesteps
#define TN ((size_t)NT * NN)   // stride between batches in x/out: 4,000,000
#define DT_F 0.02f

#define KPRE 6            // prefetched edges per lane per node (deg <= 48, ~99.7%)

// Bucketed CSR build
#define BKT_SHIFT 11
#define NBKT 25                         // ceil(50000 / 2048)
#define NBKT_PAD 32                     // mod-8-aligned for XCD pinning
#define BKT_CAP 72000                   // mean 65.5K, sigma ~253 -> 17+ sigma
#define ACHUNK 1024                     // edges staged per block-iteration in fillA
#define BPB 64                          // blocks per bucket in fillB

// ---------------------------------------------------------------------------
// Setup kernels (rebuilt every call).
// ---------------------------------------------------------------------------

__global__ void init_nodes_kernel(const float* __restrict__ bias,
                                  const float* __restrict__ tc,
                                  float* __restrict__ v0,
                                  ushort* __restrict__ r0,
                                  float* __restrict__ alpha,
                                  int* __restrict__ cnt,
                                  int* __restrict__ bucket_cursor) {
  int n = blockIdx.x * blockDim.x + threadIdx.x;
  if (n >= NN) return;
  float b = bias[n];
  __hip_bfloat16 rb = __float2bfloat16(fmaxf(b, 0.f));
  ushort rbu = *(ushort*)&rb;
#pragma unroll
  for (int j = 0; j < NB; ++j) {
    v0[(size_t)n * NB + j] = b;
    r0[(size_t)n * NB + j] = rbu;
  }
  alpha[n] = DT_F / fmaxf(tc[n], DT_F);
  cnt[n] = 0;
  if (n < NBKT_PAD) bucket_cursor[n] = 0;
}

// ---- fallback path kernels (used only if ws_size too small) ----
__global__ void hist_kernel(const int* __restrict__ tgt, int* __restrict__ cnt) {
  int e = blockIdx.x * blockDim.x + threadIdx.x;
  if (e >= NE) return;
  atomicAdd(&cnt[tgt[e]], 1);
}

__global__ void fill_kernel(const int* __restrict__ src, const int* __restrict__ tgt,
                            const float* __restrict__ sgn, const float* __restrict__ syn_cnt,
                            const float* __restrict__ syn_str,
                            int* __restrict__ cursor,
                            int2* __restrict__ csr) {
  int e = blockIdx.x * blockDim.x + threadIdx.x;
  if (e >= NE) return;
  int t = tgt[e];
  float w = sgn[e] * syn_cnt[e] * fmaxf(syn_str[e], 0.f);
  int pos = atomicAdd(&cursor[t], 1);
  csr[pos] = make_int2(src[e] * (NB * 2), __float_as_int(w));
}

// ---- fillA: bucketize edges by target-range + fused node histogram ----
__global__ __launch_bounds__(256) void fillA_kernel(
    const int* __restrict__ src, const int* __restrict__ tgt,
    const float* __restrict__ sgn, const float* __restrict__ syn_cnt,
    const float* __restrict__ syn_str,
    int* __restrict__ node_cnt,
    int* __restrict__ bucket_cursor,
    unsigned long long* __restrict__ bkt) {
  __shared__ int bcnt[NBKT];
  __shared__ int bbase[NBKT];
  __shared__ int bpos[NBKT + 1];
  __shared__ unsigned long long stage[ACHUNK];
  __shared__ unsigned char stageb[ACHUNK];

  const int tid = threadIdx.x;
  const int base = blockIdx.x * ACHUNK;

  int b_[4], off_[4];
  unsigned long long ent_[4];
  bool val_[4];
#pragma unroll
  for (int k = 0; k < 4; ++k) {
    int e = base + k * 256 + tid;
    val_[k] = e < NE;
    b_[k] = 0;
    ent_[k] = 0;
    if (val_[k]) {
      int s = src[e];
      int t = tgt[e];
      float w = sgn[e] * syn_cnt[e] * fmaxf(syn_str[e], 0.f);
      atomicAdd(&node_cnt[t], 1);
      b_[k] = t >> BKT_SHIFT;
      unsigned int packed = (unsigned int)s | ((unsigned int)(t & ((1 << BKT_SHIFT) - 1)) << 16);
      ent_[k] = ((unsigned long long)(unsigned int)__float_as_int(w) << 32) | packed;
    }
  }

  if (tid < NBKT) bcnt[tid] = 0;
  __syncthreads();
#pragma unroll
  for (int k = 0; k < 4; ++k)
    if (val_[k]) off_[k] = atomicAdd(&bcnt[b_[k]], 1);
  __syncthreads();
  if (tid == 0) {
    int run = 0;
    for (int i = 0; i < NBKT; ++i) { bpos[i] = run; run += bcnt[i]; }
    bpos[NBKT] = run;
  }
  __syncthreads();
  if (tid < NBKT) bbase[tid] = atomicAdd(&bucket_cursor[tid], bcnt[tid]);
#pragma unroll
  for (int k = 0; k < 4; ++k) {
    if (val_[k]) {
      int slot = bpos[b_[k]] + off_[k];
      stage[slot] = ent_[k];
      stageb[slot] = (unsigned char)b_[k];
    }
  }
  __syncthreads();
  const int tot = bpos[NBKT];
  for (int i = tid; i < tot; i += 256) {
    int bb = stageb[i];
    int dst = bbase[bb] + (i - bpos[bb]);
    if (dst < BKT_CAP)
      bkt[(size_t)bb * BKT_CAP + dst] = stage[i];
  }
}

// ---- fillB: scatter bucket entries into CSR (bucket pinned to one XCD) ----
__global__ __launch_bounds__(256) void fillB_kernel(
    const unsigned long long* __restrict__ bkt,
    const int* __restrict__ bucket_cursor,
    int* __restrict__ cursor,
    int2* __restrict__ csr) {
  const int b = blockIdx.x & (NBKT_PAD - 1);
  if (b >= NBKT) return;
  const int j = blockIdx.x >> 5;
  const int count = bucket_cursor[b];
  const unsigned long long* mybkt = bkt + (size_t)b * BKT_CAP;
  for (int i = j * 256 + threadIdx.x; i < count; i += BPB * 256) {
    unsigned long long ent = mybkt[i];
    unsigned int packed = (unsigned int)ent;
    int w_bits = (int)(ent >> 32);
    int s = packed & 0xFFFF;
    int t = (b << BKT_SHIFT) + ((packed >> 16) & ((1 << BKT_SHIFT) - 1));
    int pos = atomicAdd(&cursor[t], 1);
    csr[pos] = make_int2(s * (NB * 2), w_bits);
  }
}

// --- hierarchical 3-phase scan over NN counts ---
#define SCAN_BS 256
#define SCAN_NB ((NN + SCAN_BS - 1) / SCAN_BS)   // 196 blocks

__global__ __launch_bounds__(SCAN_BS) void scan1_kernel(
    const int* __restrict__ cnt, int* __restrict__ escan,
    int* __restrict__ partials) {
  __shared__ int buf[2][SCAN_BS];
  const int tid = threadIdx.x;
  const int i = blockIdx.x * SCAN_BS + tid;
  int v = (i < NN) ? cnt[i] : 0;
  int sel = 0;
  buf[0][tid] = v;
  __syncthreads();
#pragma unroll
  for (int off = 1; off < SCAN_BS; off <<= 1) {
    int s = buf[sel][tid];
    if (tid >= off) s += buf[sel][tid - off];
    buf[sel ^ 1][tid] = s;
    sel ^= 1;
    __syncthreads();
  }
  int incl = buf[sel][tid];
  if (i < NN) escan[i] = incl - v;
  if (tid == SCAN_BS - 1) partials[blockIdx.x] = incl;
}

__global__ __launch_bounds__(SCAN_BS) void scan2_kernel(
    int* __restrict__ partials, int* __restrict__ row_ptr) {
  __shared__ int buf[2][SCAN_BS];
  const int tid = threadIdx.x;
  int v = (tid < SCAN_NB) ? partials[tid] : 0;
  int sel = 0;
  buf[0][tid] = v;
  __syncthreads();
#pragma unroll
  for (int off = 1; off < SCAN_BS; off <<= 1) {
    int s = buf[sel][tid];
    if (tid >= off) s += buf[sel][tid - off];
    buf[sel ^ 1][tid] = s;
    sel ^= 1;
    __syncthreads();
  }
  int incl = buf[sel][tid];
  if (tid < SCAN_NB) partials[tid] = incl - v;
  if (tid == SCAN_BS - 1) row_ptr[NN] = incl;
}

__global__ __launch_bounds__(SCAN_BS) void scan3_kernel(
    const int* __restrict__ escan, const int* __restrict__ partials,
    int* __restrict__ row_ptr, int* __restrict__ cursor) {
  const int i = blockIdx.x * SCAN_BS + threadIdx.x;
  if (i >= NN) return;
  int r = escan[i] + partials[blockIdx.x];
  row_ptr[i] = r;
  cursor[i] = r;
}

// ---------------------------------------------------------------------------
// Per-timestep fused kernel, 2 nodes per 8-lane group:
//   - 12 independent CSR loads then 12 independent gathers outstanding
//     (2x memory-level parallelism per wave vs 1-node version);
//   - row_ptr/param loads amortized over 2 nodes;
//   - x load / out store are 8B nontemporal via unsigned long long
//     (builtin rejects HIP_vector_type pointers) -> 64B/wave full lines.
// ---------------------------------------------------------------------------
__global__ __launch_bounds__(256) void step1_kernel(
    const int* __restrict__ row_ptr,
    const int2* __restrict__ csr,
    const float* __restrict__ v_old,
    const ushort* __restrict__ r_old,   // bf16 relu state, node-major (N,8)
    float* __restrict__ v_new,
    ushort* __restrict__ r_new,
    const float* __restrict__ x_t,      // x + t*NN; batch stride TN
    const float* __restrict__ bias,
    const float* __restrict__ alpha,
    float* __restrict__ out_t) {        // out + t*NN; batch stride TN
  int gid = blockIdx.x * blockDim.x + threadIdx.x;
  int grp = gid >> 3;
  int lane = gid & 7;
  if (grp >= NN / 2) return;
  int nA = grp * 2;
  int nB = nA + 1;

  // row pointers: {eA0, eA1} as one 8B load, eB1 scalar
  int2 rpA = *(const int2*)(row_ptr + nA);
  int eB1 = row_ptr[nB + 1];
  int eA0 = rpA.x, eA1 = rpA.y;

  int mybaseA = eA0 + lane;
  int remA = eA1 - mybaseA;
  int cntA = remA > 0 ? ((remA + 7) >> 3) : 0;
  int mybaseB = eA1 + lane;
  int remB = eB1 - mybaseB;
  int cntB = remB > 0 ? ((remB + 7) >> 3) : 0;

  // node params / state (independent loads, issued early)
  float2 al = *(const float2*)(alpha + nA);
  float2 bsv = *(const float2*)(bias + nA);
  size_t idxA = (size_t)nA * NB + lane;
  size_t idxB = (size_t)nB * NB + lane;
  size_t boff = (size_t)lane * TN + nA;   // 8B covers nA, nB
  float vA = v_old[idxA];
  float vB = v_old[idxB];
  unsigned long long xbits =
      __builtin_nontemporal_load((const unsigned long long*)(x_t + boff));
  float xvA = __uint_as_float((unsigned int)xbits);
  float xvB = __uint_as_float((unsigned int)(xbits >> 32));

  // 12 independent CSR loads
  int soffA[KPRE], soffB[KPRE];
  float wkA[KPRE], wkB[KPRE];
#pragma unroll
  for (int k = 0; k < KPRE; ++k) {
    int2 c = (k < cntA) ? csr[mybaseA + (k << 3)] : make_int2(0, 0);
    soffA[k] = c.x;
    wkA[k] = __int_as_float(c.y);
  }
#pragma unroll
  for (int k = 0; k < KPRE; ++k) {
    int2 c = (k < cntB) ? csr[mybaseB + (k << 3)] : make_int2(0, 0);
    soffB[k] = c.x;
    wkB[k] = __int_as_float(c.y);
  }

  // 12 independent predicated gathers
  uint4 rvA[KPRE], rvB[KPRE];
#pragma unroll
  for (int k = 0; k < KPRE; ++k) {
    if (k < cntA) rvA[k] = *(const uint4*)((const char*)r_old + soffA[k]);
    else rvA[k] = make_uint4(0, 0, 0, 0);
  }
#pragma unroll
  for (int k = 0; k < KPRE; ++k) {
    if (k < cntB) rvB[k] = *(const uint4*)((const char*)r_old + soffB[k]);
    else rvB[k] = make_uint4(0, 0, 0, 0);
  }

  float accA[NB], accB[NB];
#pragma unroll
  for (int j = 0; j < NB; ++j) { accA[j] = 0.f; accB[j] = 0.f; }

#pragma unroll
  for (int k = 0; k < KPRE; ++k) {
    float w = wkA[k];
    accA[0] += w * __uint_as_float(rvA[k].x << 16);
    accA[1] += w * __uint_as_float(rvA[k].x & 0xffff0000u);
    accA[2] += w * __uint_as_float(rvA[k].y << 16);
    accA[3] += w * __uint_as_float(rvA[k].y & 0xffff0000u);
    accA[4] += w * __uint_as_float(rvA[k].z << 16);
    accA[5] += w * __uint_as_float(rvA[k].z & 0xffff0000u);
    accA[6] += w * __uint_as_float(rvA[k].w << 16);
    accA[7] += w * __uint_as_float(rvA[k].w & 0xffff0000u);
  }
#pragma unroll
  for (int k = 0; k < KPRE; ++k) {
    float w = wkB[k];
    accB[0] += w * __uint_as_float(rvB[k].x << 16);
    accB[1] += w * __uint_as_float(rvB[k].x & 0xffff0000u);
    accB[2] += w * __uint_as_float(rvB[k].y << 16);
    accB[3] += w * __uint_as_float(rvB[k].y & 0xffff0000u);
    accB[4] += w * __uint_as_float(rvB[k].z << 16);
    accB[5] += w * __uint_as_float(rvB[k].z & 0xffff0000u);
    accB[6] += w * __uint_as_float(rvB[k].w << 16);
    accB[7] += w * __uint_as_float(rvB[k].w & 0xffff0000u);
  }

  // overflow edges (deg > 48; ~0.3% of nodes)
  for (int e = mybaseA + (KPRE << 3); e < eA1; e += 8) {
    int2 c = csr[e];
    uint4 r8 = *(const uint4*)((const char*)r_old + c.x);
    float w = __int_as_float(c.y);
    accA[0] += w * __uint_as_float(r8.x << 16);
    accA[1] += w * __uint_as_float(r8.x & 0xffff0000u);
    accA[2] += w * __uint_as_float(r8.y << 16);
    accA[3] += w * __uint_as_float(r8.y & 0xffff0000u);
    accA[4] += w * __uint_as_float(r8.z << 16);
    accA[5] += w * __uint_as_float(r8.z & 0xffff0000u);
    accA[6] += w * __uint_as_float(r8.w << 16);
    accA[7] += w * __uint_as_float(r8.w & 0xffff0000u);
  }
  for (int e = mybaseB + (KPRE << 3); e < eB1; e += 8) {
    int2 c = csr[e];
    uint4 r8 = *(const uint4*)((const char*)r_old + c.x);
    float w = __int_as_float(c.y);
    accB[0] += w * __uint_as_float(r8.x << 16);
    accB[1] += w * __uint_as_float(r8.x & 0xffff0000u);
    accB[2] += w * __uint_as_float(r8.y << 16);
    accB[3] += w * __uint_as_float(r8.y & 0xffff0000u);
    accB[4] += w * __uint_as_float(r8.z << 16);
    accB[5] += w * __uint_as_float(r8.z & 0xffff0000u);
    accB[6] += w * __uint_as_float(r8.w << 16);
    accB[7] += w * __uint_as_float(r8.w & 0xffff0000u);
  }

  // butterfly reduce across the 8-lane group; lane l ends with valid acc[l]
#pragma unroll
  for (int off = 4; off; off >>= 1) {
#pragma unroll
    for (int j = 0; j < NB; ++j) {
      float tA = __shfl_xor(accA[j], off);
      float tB = __shfl_xor(accB[j], off);
      bool keep = ((lane ^ j) & off) == 0;
      accA[j] = keep ? accA[j] + tA : accA[j];
      accB[j] = keep ? accB[j] + tB : accB[j];
    }
  }
  float rA = accA[0], rB = accB[0];
#pragma unroll
  for (int j = 1; j < NB; ++j) {
    rA = (lane == j) ? accA[j] : rA;
    rB = (lane == j) ? accB[j] : rB;
  }

  float vnA = vA + al.x * (bsv.x - vA + rA + xvA);
  float vnB = vB + al.y * (bsv.y - vB + rB + xvB);
  v_new[idxA] = vnA;
  v_new[idxB] = vnB;
  __hip_bfloat16 rhA = __float2bfloat16(fmaxf(vnA, 0.f));
  __hip_bfloat16 rhB = __float2bfloat16(fmaxf(vnB, 0.f));
  r_new[idxA] = *(ushort*)&rhA;
  r_new[idxB] = *(ushort*)&rhB;
  unsigned long long obits =
      (unsigned long long)__float_as_uint(vnA) |
      ((unsigned long long)__float_as_uint(vnB) << 32);
  __builtin_nontemporal_store(obits, (unsigned long long*)(out_t + boff));
}

// ---------------------------------------------------------------------------

extern "C" void kernel_launch(void* const* d_in, const int* in_sizes, int n_in,
                              void* d_out, int out_size, void* d_ws, size_t ws_size,
                              hipStream_t stream) {
  const float* x        = (const float*)d_in[0];
  const float* bias     = (const float*)d_in[1];
  const float* tc       = (const float*)d_in[2];
  const float* sgn      = (const float*)d_in[3];
  const float* syn_cnt  = (const float*)d_in[4];
  const float* syn_str  = (const float*)d_in[5];
  const int*   src      = (const int*)d_in[6];
  const int*   tgt      = (const int*)d_in[7];
  float* out = (float*)d_out;

  char* p = (char*)d_ws;
  auto take = [&p](size_t bytes) {
    char* r = p;
    p += (bytes + 255) & ~(size_t)255;
    return (void*)r;
  };
  float*  v_a      = (float*)take((size_t)NN * NB * sizeof(float));
  float*  v_b      = (float*)take((size_t)NN * NB * sizeof(float));
  ushort* r_a      = (ushort*)take((size_t)NN * NB * sizeof(ushort));
  ushort* r_b      = (ushort*)take((size_t)NN * NB * sizeof(ushort));
  float*  alpha    = (float*)take((size_t)NN * sizeof(float));
  int*    row_ptr  = (int*)take(((size_t)NN + 1) * sizeof(int));
  int*    cnt      = (int*)take((size_t)NN * sizeof(int));
  int*    cursor   = (int*)take((size_t)NN * sizeof(int));
  int*    escan    = (int*)take((size_t)NN * sizeof(int));
  int*    partials = (int*)take((size_t)SCAN_NB * sizeof(int));
  int*    bcur     = (int*)take((size_t)NBKT_PAD * sizeof(int));
  int2*   csr      = (int2*)take((size_t)NE * sizeof(int2));
  unsigned long long* bkt =
      (unsigned long long*)take((size_t)NBKT * BKT_CAP * sizeof(unsigned long long));
  const bool use_bucketed = ((size_t)(p - (char*)d_ws) <= ws_size);

  init_nodes_kernel<<<(NN + 255) / 256, 256, 0, stream>>>(bias, tc, v_a, r_a,
                                                          alpha, cnt, bcur);
  if (use_bucketed) {
    fillA_kernel<<<(NE + ACHUNK - 1) / ACHUNK, 256, 0, stream>>>(
        src, tgt, sgn, syn_cnt, syn_str, cnt, bcur, bkt);
    scan1_kernel<<<SCAN_NB, SCAN_BS, 0, stream>>>(cnt, escan, partials);
    scan2_kernel<<<1, SCAN_BS, 0, stream>>>(partials, row_ptr);
    scan3_kernel<<<SCAN_NB, SCAN_BS, 0, stream>>>(escan, partials, row_ptr, cursor);
    fillB_kernel<<<NBKT_PAD * BPB, 256, 0, stream>>>(bkt, bcur, cursor, csr);
  } else {
    hist_kernel<<<(NE + 255) / 256, 256, 0, stream>>>(tgt, cnt);
    scan1_kernel<<<SCAN_NB, SCAN_BS, 0, stream>>>(cnt, escan, partials);
    scan2_kernel<<<1, SCAN_BS, 0, stream>>>(partials, row_ptr);
    scan3_kernel<<<SCAN_NB, SCAN_BS, 0, stream>>>(escan, partials, row_ptr, cursor);
    fill_kernel<<<(NE + 255) / 256, 256, 0, stream>>>(src, tgt, sgn, syn_cnt,
                                                      syn_str, cursor, csr);
  }

  // Sequential Euler steps; 2 nodes per 8-lane group, 200K threads.
  const int blocks = (NN / 2 * 8 + 255) / 256;
  const float* vin = v_a;
  float* vout = v_b;
  const ushort* rin = r_a;
  ushort* rout = r_b;
  for (int t = 0; t < NT; ++t) {
    step1_kernel<<<blocks, 256, 0, stream>>>(
        row_ptr, csr, vin, rin, vout, rout,
        x + (size_t)t * NN, bias, alpha, out + (size_t)t * NN);
    float* tv = (float*)vin; vin = vout; vout = tv;
    ushort* tr = (ushort*)rin; rin = rout; rout = tr;
  }
}

// Round 10
// 1251.810 us; speedup vs baseline: 1.0265x; 1.0265x over previous
//
#include <hip/hip_runtime.h>
#include <hip/hip_bf16.h>

// Problem constants (Network_29197187678952)
#define NN 50000          // nodes
#define NE 1600000        // edges
#define NB 8              // batch
#define NT 80             // timesteps
#define TN ((size_t)NT * NN)   // stride between batches in x/out: 4,000,000
#define DT_F 0.02f

#define LPN 16            // lanes (threads) per node in the step kernel
#define KPRE 3            // prefetched edges per lane (deg <= 48, ~99.7%)

// Bucketed CSR build
#define BKT_SHIFT 11
#define NBKT 25                         // ceil(50000 / 2048)
#define NBKT_PAD 32                     // mod-8-aligned for XCD pinning
#define BKT_CAP 72000                   // mean 65.5K, sigma ~253 -> 17+ sigma
#define ACHUNK 1024                     // edges staged per block-iteration in fillA
#define BPB 64                          // blocks per bucket in fillB

// ---------------------------------------------------------------------------
// Setup kernels (rebuilt every call).
// ---------------------------------------------------------------------------

__global__ void init_nodes_kernel(const float* __restrict__ bias,
                                  const float* __restrict__ tc,
                                  float* __restrict__ v0,
                                  ushort* __restrict__ r0,
                                  float* __restrict__ alpha,
                                  int* __restrict__ cnt,
                                  int* __restrict__ bucket_cursor) {
  int n = blockIdx.x * blockDim.x + threadIdx.x;
  if (n >= NN) return;
  float b = bias[n];
  __hip_bfloat16 rb = __float2bfloat16(fmaxf(b, 0.f));
  ushort rbu = *(ushort*)&rb;
#pragma unroll
  for (int j = 0; j < NB; ++j) {
    v0[(size_t)n * NB + j] = b;
    r0[(size_t)n * NB + j] = rbu;
  }
  alpha[n] = DT_F / fmaxf(tc[n], DT_F);
  cnt[n] = 0;
  if (n < NBKT_PAD) bucket_cursor[n] = 0;
}

// ---- fallback path kernels (used only if ws_size too small) ----
__global__ void hist_kernel(const int* __restrict__ tgt, int* __restrict__ cnt) {
  int e = blockIdx.x * blockDim.x + threadIdx.x;
  if (e >= NE) return;
  atomicAdd(&cnt[tgt[e]], 1);
}

__global__ void fill_kernel(const int* __restrict__ src, const int* __restrict__ tgt,
                            const float* __restrict__ sgn, const float* __restrict__ syn_cnt,
                            const float* __restrict__ syn_str,
                            int* __restrict__ cursor,
                            int2* __restrict__ csr) {
  int e = blockIdx.x * blockDim.x + threadIdx.x;
  if (e >= NE) return;
  int t = tgt[e];
  float w = sgn[e] * syn_cnt[e] * fmaxf(syn_str[e], 0.f);
  int pos = atomicAdd(&cursor[t], 1);
  csr[pos] = make_int2(src[e] * (NB * 2), __float_as_int(w));
}

// ---- fillA: bucketize edges by target-range + fused node histogram ----
__global__ __launch_bounds__(256) void fillA_kernel(
    const int* __restrict__ src, const int* __restrict__ tgt,
    const float* __restrict__ sgn, const float* __restrict__ syn_cnt,
    const float* __restrict__ syn_str,
    int* __restrict__ node_cnt,
    int* __restrict__ bucket_cursor,
    unsigned long long* __restrict__ bkt) {
  __shared__ int bcnt[NBKT];
  __shared__ int bbase[NBKT];
  __shared__ int bpos[NBKT + 1];
  __shared__ unsigned long long stage[ACHUNK];
  __shared__ unsigned char stageb[ACHUNK];

  const int tid = threadIdx.x;
  const int base = blockIdx.x * ACHUNK;

  int b_[4], off_[4];
  unsigned long long ent_[4];
  bool val_[4];
#pragma unroll
  for (int k = 0; k < 4; ++k) {
    int e = base + k * 256 + tid;
    val_[k] = e < NE;
    b_[k] = 0;
    ent_[k] = 0;
    if (val_[k]) {
      int s = src[e];
      int t = tgt[e];
      float w = sgn[e] * syn_cnt[e] * fmaxf(syn_str[e], 0.f);
      atomicAdd(&node_cnt[t], 1);
      b_[k] = t >> BKT_SHIFT;
      unsigned int packed = (unsigned int)s | ((unsigned int)(t & ((1 << BKT_SHIFT) - 1)) << 16);
      ent_[k] = ((unsigned long long)(unsigned int)__float_as_int(w) << 32) | packed;
    }
  }

  if (tid < NBKT) bcnt[tid] = 0;
  __syncthreads();
#pragma unroll
  for (int k = 0; k < 4; ++k)
    if (val_[k]) off_[k] = atomicAdd(&bcnt[b_[k]], 1);
  __syncthreads();
  if (tid == 0) {
    int run = 0;
    for (int i = 0; i < NBKT; ++i) { bpos[i] = run; run += bcnt[i]; }
    bpos[NBKT] = run;
  }
  __syncthreads();
  if (tid < NBKT) bbase[tid] = atomicAdd(&bucket_cursor[tid], bcnt[tid]);
#pragma unroll
  for (int k = 0; k < 4; ++k) {
    if (val_[k]) {
      int slot = bpos[b_[k]] + off_[k];
      stage[slot] = ent_[k];
      stageb[slot] = (unsigned char)b_[k];
    }
  }
  __syncthreads();
  const int tot = bpos[NBKT];
  for (int i = tid; i < tot; i += 256) {
    int bb = stageb[i];
    int dst = bbase[bb] + (i - bpos[bb]);
    if (dst < BKT_CAP)
      bkt[(size_t)bb * BKT_CAP + dst] = stage[i];
  }
}

// ---- fillB: scatter bucket entries into CSR (bucket pinned to one XCD) ----
__global__ __launch_bounds__(256) void fillB_kernel(
    const unsigned long long* __restrict__ bkt,
    const int* __restrict__ bucket_cursor,
    int* __restrict__ cursor,
    int2* __restrict__ csr) {
  const int b = blockIdx.x & (NBKT_PAD - 1);
  if (b >= NBKT) return;
  const int j = blockIdx.x >> 5;
  const int count = bucket_cursor[b];
  const unsigned long long* mybkt = bkt + (size_t)b * BKT_CAP;
  for (int i = j * 256 + threadIdx.x; i < count; i += BPB * 256) {
    unsigned long long ent = mybkt[i];
    unsigned int packed = (unsigned int)ent;
    int w_bits = (int)(ent >> 32);
    int s = packed & 0xFFFF;
    int t = (b << BKT_SHIFT) + ((packed >> 16) & ((1 << BKT_SHIFT) - 1));
    int pos = atomicAdd(&cursor[t], 1);
    csr[pos] = make_int2(s * (NB * 2), w_bits);
  }
}

// --- hierarchical 3-phase scan over NN counts ---
#define SCAN_BS 256
#define SCAN_NB ((NN + SCAN_BS - 1) / SCAN_BS)   // 196 blocks

__global__ __launch_bounds__(SCAN_BS) void scan1_kernel(
    const int* __restrict__ cnt, int* __restrict__ escan,
    int* __restrict__ partials) {
  __shared__ int buf[2][SCAN_BS];
  const int tid = threadIdx.x;
  const int i = blockIdx.x * SCAN_BS + tid;
  int v = (i < NN) ? cnt[i] : 0;
  int sel = 0;
  buf[0][tid] = v;
  __syncthreads();
#pragma unroll
  for (int off = 1; off < SCAN_BS; off <<= 1) {
    int s = buf[sel][tid];
    if (tid >= off) s += buf[sel][tid - off];
    buf[sel ^ 1][tid] = s;
    sel ^= 1;
    __syncthreads();
  }
  int incl = buf[sel][tid];
  if (i < NN) escan[i] = incl - v;
  if (tid == SCAN_BS - 1) partials[blockIdx.x] = incl;
}

__global__ __launch_bounds__(SCAN_BS) void scan2_kernel(
    int* __restrict__ partials, int* __restrict__ row_ptr) {
  __shared__ int buf[2][SCAN_BS];
  const int tid = threadIdx.x;
  int v = (tid < SCAN_NB) ? partials[tid] : 0;
  int sel = 0;
  buf[0][tid] = v;
  __syncthreads();
#pragma unroll
  for (int off = 1; off < SCAN_BS; off <<= 1) {
    int s = buf[sel][tid];
    if (tid >= off) s += buf[sel][tid - off];
    buf[sel ^ 1][tid] = s;
    sel ^= 1;
    __syncthreads();
  }
  int incl = buf[sel][tid];
  if (tid < SCAN_NB) partials[tid] = incl - v;
  if (tid == SCAN_BS - 1) row_ptr[NN] = incl;
}

__global__ __launch_bounds__(SCAN_BS) void scan3_kernel(
    const int* __restrict__ escan, const int* __restrict__ partials,
    int* __restrict__ row_ptr, int* __restrict__ cursor) {
  const int i = blockIdx.x * SCAN_BS + threadIdx.x;
  if (i >= NN) return;
  int r = escan[i] + partials[blockIdx.x];
  row_ptr[i] = r;
  cursor[i] = r;
}

// ---------------------------------------------------------------------------
// Per-timestep fused kernel, 16 lanes per node (R10 experiment: more TLP).
// Each lane prefetches <=KPRE=3 CSR entries + gathers; reduce = 1
// unconditional stage (off=8, merge lane halves) + 3-stage batch butterfly;
// low 8 lanes of each 16-lane group do the Euler update for batch sub=lane&7.
// ---------------------------------------------------------------------------
__global__ __launch_bounds__(256) void step1_kernel(
    const int* __restrict__ row_ptr,
    const int2* __restrict__ csr,
    const float* __restrict__ v_old,
    const ushort* __restrict__ r_old,   // bf16 relu state, node-major (N,8)
    float* __restrict__ v_new,
    ushort* __restrict__ r_new,
    const float* __restrict__ x_t,      // x + t*NN; batch stride TN
    const float* __restrict__ bias,
    const float* __restrict__ alpha,
    float* __restrict__ out_t) {        // out + t*NN; batch stride TN
  int gid = blockIdx.x * blockDim.x + threadIdx.x;
  int node = gid >> 4;
  int lane = gid & 15;
  int sub = lane & 7;
  int hi = lane >> 3;
  if (node >= NN) return;

  int e0 = row_ptr[node];
  int e1 = row_ptr[node + 1];
  int mybase = e0 + lane;
  int rem = e1 - mybase;
  int cnt = rem > 0 ? ((rem + LPN - 1) >> 4) : 0;   // my edge count (stride 16)

  // node-state loads (only the low half needs them; predication saves requests)
  float a = 0.f, bs = 0.f, v = 0.f, xv = 0.f;
  size_t idx = (size_t)node * NB + sub;
  size_t boff = (size_t)sub * TN + node;
  if (hi == 0) {
    a = alpha[node];
    bs = bias[node];
    v = v_old[idx];
    xv = __builtin_nontemporal_load(&x_t[boff]);
  }

  // prefetch CSR entries (independent, exec-masked per slot)
  int soff[KPRE];
  float wk[KPRE];
#pragma unroll
  for (int k = 0; k < KPRE; ++k) {
    int2 c = (k < cnt) ? csr[mybase + (k << 4)] : make_int2(0, 0);
    soff[k] = c.x;
    wk[k] = __int_as_float(c.y);
  }

  // predicated independent gathers
  uint4 rv[KPRE];
#pragma unroll
  for (int k = 0; k < KPRE; ++k) {
    if (k < cnt)
      rv[k] = *(const uint4*)((const char*)r_old + soff[k]);
    else
      rv[k] = make_uint4(0, 0, 0, 0);
  }

  float acc[NB];
#pragma unroll
  for (int j = 0; j < NB; ++j) acc[j] = 0.f;

#pragma unroll
  for (int k = 0; k < KPRE; ++k) {
    float w = wk[k];
    acc[0] += w * __uint_as_float(rv[k].x << 16);
    acc[1] += w * __uint_as_float(rv[k].x & 0xffff0000u);
    acc[2] += w * __uint_as_float(rv[k].y << 16);
    acc[3] += w * __uint_as_float(rv[k].y & 0xffff0000u);
    acc[4] += w * __uint_as_float(rv[k].z << 16);
    acc[5] += w * __uint_as_float(rv[k].z & 0xffff0000u);
    acc[6] += w * __uint_as_float(rv[k].w << 16);
    acc[7] += w * __uint_as_float(rv[k].w & 0xffff0000u);
  }

  // overflow edges (deg > 48; ~0.3% of nodes)
  for (int e = mybase + (KPRE << 4); e < e1; e += LPN) {
    int2 c = csr[e];
    uint4 r8 = *(const uint4*)((const char*)r_old + c.x);
    float w = __int_as_float(c.y);
    acc[0] += w * __uint_as_float(r8.x << 16);
    acc[1] += w * __uint_as_float(r8.x & 0xffff0000u);
    acc[2] += w * __uint_as_float(r8.y << 16);
    acc[3] += w * __uint_as_float(r8.y & 0xffff0000u);
    acc[4] += w * __uint_as_float(r8.z << 16);
    acc[5] += w * __uint_as_float(r8.z & 0xffff0000u);
    acc[6] += w * __uint_as_float(r8.w << 16);
    acc[7] += w * __uint_as_float(r8.w & 0xffff0000u);
  }

  // stage 1: merge the two 8-lane halves (unconditional add)
#pragma unroll
  for (int j = 0; j < NB; ++j) acc[j] += __shfl_xor(acc[j], 8);

  // stages 2-4: batch-split butterfly within 8 lanes; lane sub ends with acc[sub]
#pragma unroll
  for (int off = 4; off; off >>= 1) {
#pragma unroll
    for (int j = 0; j < NB; ++j) {
      float t = __shfl_xor(acc[j], off);
      acc[j] = (((sub ^ j) & off) == 0) ? acc[j] + t : acc[j];
    }
  }
  float r = acc[0];
#pragma unroll
  for (int j = 1; j < NB; ++j) r = (sub == j) ? acc[j] : r;

  if (hi == 0) {
    float vn = v + a * (bs - v + r + xv);
    v_new[idx] = vn;
    __hip_bfloat16 rh = __float2bfloat16(fmaxf(vn, 0.f));
    r_new[idx] = *(ushort*)&rh;
    __builtin_nontemporal_store(vn, &out_t[boff]);
  }
}

// ---------------------------------------------------------------------------

extern "C" void kernel_launch(void* const* d_in, const int* in_sizes, int n_in,
                              void* d_out, int out_size, void* d_ws, size_t ws_size,
                              hipStream_t stream) {
  const float* x        = (const float*)d_in[0];
  const float* bias     = (const float*)d_in[1];
  const float* tc       = (const float*)d_in[2];
  const float* sgn      = (const float*)d_in[3];
  const float* syn_cnt  = (const float*)d_in[4];
  const float* syn_str  = (const float*)d_in[5];
  const int*   src      = (const int*)d_in[6];
  const int*   tgt      = (const int*)d_in[7];
  float* out = (float*)d_out;

  char* p = (char*)d_ws;
  auto take = [&p](size_t bytes) {
    char* r = p;
    p += (bytes + 255) & ~(size_t)255;
    return (void*)r;
  };
  float*  v_a      = (float*)take((size_t)NN * NB * sizeof(float));
  float*  v_b      = (float*)take((size_t)NN * NB * sizeof(float));
  ushort* r_a      = (ushort*)take((size_t)NN * NB * sizeof(ushort));
  ushort* r_b      = (ushort*)take((size_t)NN * NB * sizeof(ushort));
  float*  alpha    = (float*)take((size_t)NN * sizeof(float));
  int*    row_ptr  = (int*)take(((size_t)NN + 1) * sizeof(int));
  int*    cnt      = (int*)take((size_t)NN * sizeof(int));
  int*    cursor   = (int*)take((size_t)NN * sizeof(int));
  int*    escan    = (int*)take((size_t)NN * sizeof(int));
  int*    partials = (int*)take((size_t)SCAN_NB * sizeof(int));
  int*    bcur     = (int*)take((size_t)NBKT_PAD * sizeof(int));
  int2*   csr      = (int2*)take((size_t)NE * sizeof(int2));
  unsigned long long* bkt =
      (unsigned long long*)take((size_t)NBKT * BKT_CAP * sizeof(unsigned long long));
  const bool use_bucketed = ((size_t)(p - (char*)d_ws) <= ws_size);

  init_nodes_kernel<<<(NN + 255) / 256, 256, 0, stream>>>(bias, tc, v_a, r_a,
                                                          alpha, cnt, bcur);
  if (use_bucketed) {
    fillA_kernel<<<(NE + ACHUNK - 1) / ACHUNK, 256, 0, stream>>>(
        src, tgt, sgn, syn_cnt, syn_str, cnt, bcur, bkt);
    scan1_kernel<<<SCAN_NB, SCAN_BS, 0, stream>>>(cnt, escan, partials);
    scan2_kernel<<<1, SCAN_BS, 0, stream>>>(partials, row_ptr);
    scan3_kernel<<<SCAN_NB, SCAN_BS, 0, stream>>>(escan, partials, row_ptr, cursor);
    fillB_kernel<<<NBKT_PAD * BPB, 256, 0, stream>>>(bkt, bcur, cursor, csr);
  } else {
    hist_kernel<<<(NE + 255) / 256, 256, 0, stream>>>(tgt, cnt);
    scan1_kernel<<<SCAN_NB, SCAN_BS, 0, stream>>>(cnt, escan, partials);
    scan2_kernel<<<1, SCAN_BS, 0, stream>>>(partials, row_ptr);
    scan3_kernel<<<SCAN_NB, SCAN_BS, 0, stream>>>(escan, partials, row_ptr, cursor);
    fill_kernel<<<(NE + 255) / 256, 256, 0, stream>>>(src, tgt, sgn, syn_cnt,
                                                      syn_str, cursor, csr);
  }

  // Sequential Euler steps; 16 lanes/node, 800K threads, plain launches.
  const int blocks = ((size_t)NN * LPN + 255) / 256;
  const float* vin = v_a;
  float* vout = v_b;
  const ushort* rin = r_a;
  ushort* rout = r_b;
  for (int t = 0; t < NT; ++t) {
    step1_kernel<<<blocks, 256, 0, stream>>>(
        row_ptr, csr, vin, rin, vout, rout,
        x + (size_t)t * NN, bias, alpha, out + (size_t)t * NN);
    float* tv = (float*)vin; vin = vout; vout = tv;
    ushort* tr = (ushort*)rin; rin = rout; rout = tr;
  }
}

// Round 11
// 1122.672 us; speedup vs baseline: 1.1446x; 1.1150x over previous
//
#include <hip/hip_runtime.h>
#include <hip/hip_bf16.h>

// Problem constants (Network_29197187678952)
#define NN 50000          // nodes
#define NE 1600000        // edges
#define NB 8              // batch
#define NT 80             // timesteps
#define TN ((size_t)NT * NN)   // stride between batches in x/out: 4,000,000
#define DT_F 0.02f

#define LPN 8             // lanes (threads) per node in the step kernel (R7-proven)
#define KPRE 6            // prefetched edges per lane (deg <= 48, ~99.7%)

// Bucketed CSR build
#define BKT_SHIFT 11
#define NBKT 25                         // ceil(50000 / 2048)
#define NBKT_PAD 32                     // mod-8-aligned for XCD pinning
#define BKT_CAP 72000                   // mean 65.5K, sigma ~253 -> 17+ sigma
#define ACHUNK 2048                     // edges staged per block-iteration in fillA
#define BPB 64                          // blocks per bucket in fillB

// ---------------------------------------------------------------------------
// Setup kernels (rebuilt every call).
// ---------------------------------------------------------------------------

__global__ void init_nodes_kernel(const float* __restrict__ bias,
                                  const float* __restrict__ tc,
                                  ushort* __restrict__ r0,
                                  float* __restrict__ alpha,
                                  int* __restrict__ cnt,
                                  int* __restrict__ bucket_cursor) {
  int n = blockIdx.x * blockDim.x + threadIdx.x;
  if (n >= NN) return;
  float b = bias[n];
  __hip_bfloat16 rb = __float2bfloat16(fmaxf(b, 0.f));
  ushort rbu = *(ushort*)&rb;
#pragma unroll
  for (int j = 0; j < NB; ++j) r0[(size_t)n * NB + j] = rbu;
  alpha[n] = DT_F / fmaxf(tc[n], DT_F);
  cnt[n] = 0;
  if (n < NBKT_PAD) bucket_cursor[n] = 0;
}

// ---- fallback path kernels (used only if ws_size too small) ----
__global__ void hist_kernel(const int* __restrict__ tgt, int* __restrict__ cnt) {
  int e = blockIdx.x * blockDim.x + threadIdx.x;
  if (e >= NE) return;
  atomicAdd(&cnt[tgt[e]], 1);
}

__global__ void fill_kernel(const int* __restrict__ src, const int* __restrict__ tgt,
                            const float* __restrict__ sgn, const float* __restrict__ syn_cnt,
                            const float* __restrict__ syn_str,
                            int* __restrict__ cursor,
                            unsigned int* __restrict__ csr) {
  int e = blockIdx.x * blockDim.x + threadIdx.x;
  if (e >= NE) return;
  int t = tgt[e];
  float w = sgn[e] * syn_cnt[e] * fmaxf(syn_str[e], 0.f);
  __hip_bfloat16 wh = __float2bfloat16(w);
  unsigned int wb = *(ushort*)&wh;
  int pos = atomicAdd(&cursor[t], 1);
  csr[pos] = (unsigned int)src[e] | (wb << 16);
}

// ---- fillA: bucketize edges by target-range + fused node histogram ----
__global__ __launch_bounds__(256) void fillA_kernel(
    const int* __restrict__ src, const int* __restrict__ tgt,
    const float* __restrict__ sgn, const float* __restrict__ syn_cnt,
    const float* __restrict__ syn_str,
    int* __restrict__ node_cnt,
    int* __restrict__ bucket_cursor,
    unsigned long long* __restrict__ bkt) {
  __shared__ int bcnt[NBKT];
  __shared__ int bbase[NBKT];
  __shared__ int bpos[NBKT + 1];
  __shared__ unsigned long long stage[ACHUNK];
  __shared__ unsigned char stageb[ACHUNK];

  const int tid = threadIdx.x;
  const int base = blockIdx.x * ACHUNK;
#define EPT (ACHUNK / 256)   // 8 edges per thread

  int b_[EPT], off_[EPT];
  unsigned long long ent_[EPT];
  bool val_[EPT];
#pragma unroll
  for (int k = 0; k < EPT; ++k) {
    int e = base + k * 256 + tid;
    val_[k] = e < NE;
    b_[k] = 0;
    ent_[k] = 0;
    if (val_[k]) {
      int s = src[e];
      int t = tgt[e];
      float w = sgn[e] * syn_cnt[e] * fmaxf(syn_str[e], 0.f);
      atomicAdd(&node_cnt[t], 1);
      b_[k] = t >> BKT_SHIFT;
      unsigned int packed = (unsigned int)s | ((unsigned int)(t & ((1 << BKT_SHIFT) - 1)) << 16);
      ent_[k] = ((unsigned long long)(unsigned int)__float_as_int(w) << 32) | packed;
    }
  }

  if (tid < NBKT) bcnt[tid] = 0;
  __syncthreads();
#pragma unroll
  for (int k = 0; k < EPT; ++k)
    if (val_[k]) off_[k] = atomicAdd(&bcnt[b_[k]], 1);
  __syncthreads();
  if (tid == 0) {
    int run = 0;
    for (int i = 0; i < NBKT; ++i) { bpos[i] = run; run += bcnt[i]; }
    bpos[NBKT] = run;
  }
  __syncthreads();
  if (tid < NBKT) bbase[tid] = atomicAdd(&bucket_cursor[tid], bcnt[tid]);
#pragma unroll
  for (int k = 0; k < EPT; ++k) {
    if (val_[k]) {
      int slot = bpos[b_[k]] + off_[k];
      stage[slot] = ent_[k];
      stageb[slot] = (unsigned char)b_[k];
    }
  }
  __syncthreads();
  const int tot = bpos[NBKT];
  for (int i = tid; i < tot; i += 256) {
    int bb = stageb[i];
    int dst = bbase[bb] + (i - bpos[bb]);
    if (dst < BKT_CAP)
      bkt[(size_t)bb * BKT_CAP + dst] = stage[i];
  }
#undef EPT
}

// ---- fillB: scatter bucket entries into 4B CSR (bucket pinned to one XCD) ----
__global__ __launch_bounds__(256) void fillB_kernel(
    const unsigned long long* __restrict__ bkt,
    const int* __restrict__ bucket_cursor,
    int* __restrict__ cursor,
    unsigned int* __restrict__ csr) {
  const int b = blockIdx.x & (NBKT_PAD - 1);
  if (b >= NBKT) return;
  const int j = blockIdx.x >> 5;
  const int count = bucket_cursor[b];
  const unsigned long long* mybkt = bkt + (size_t)b * BKT_CAP;
  for (int i = j * 256 + threadIdx.x; i < count; i += BPB * 256) {
    unsigned long long ent = mybkt[i];
    unsigned int packed = (unsigned int)ent;
    float w = __int_as_float((int)(ent >> 32));
    unsigned int s = packed & 0xFFFF;
    int t = (b << BKT_SHIFT) + ((packed >> 16) & ((1 << BKT_SHIFT) - 1));
    __hip_bfloat16 wh = __float2bfloat16(w);
    unsigned int wb = *(ushort*)&wh;
    int pos = atomicAdd(&cursor[t], 1);
    csr[pos] = s | (wb << 16);
  }
}

// --- hierarchical 3-phase scan over NN counts ---
#define SCAN_BS 256
#define SCAN_NB ((NN + SCAN_BS - 1) / SCAN_BS)   // 196 blocks

__global__ __launch_bounds__(SCAN_BS) void scan1_kernel(
    const int* __restrict__ cnt, int* __restrict__ escan,
    int* __restrict__ partials) {
  __shared__ int buf[2][SCAN_BS];
  const int tid = threadIdx.x;
  const int i = blockIdx.x * SCAN_BS + tid;
  int v = (i < NN) ? cnt[i] : 0;
  int sel = 0;
  buf[0][tid] = v;
  __syncthreads();
#pragma unroll
  for (int off = 1; off < SCAN_BS; off <<= 1) {
    int s = buf[sel][tid];
    if (tid >= off) s += buf[sel][tid - off];
    buf[sel ^ 1][tid] = s;
    sel ^= 1;
    __syncthreads();
  }
  int incl = buf[sel][tid];
  if (i < NN) escan[i] = incl - v;
  if (tid == SCAN_BS - 1) partials[blockIdx.x] = incl;
}

__global__ __launch_bounds__(SCAN_BS) void scan2_kernel(
    int* __restrict__ partials, int* __restrict__ row_ptr) {
  __shared__ int buf[2][SCAN_BS];
  const int tid = threadIdx.x;
  int v = (tid < SCAN_NB) ? partials[tid] : 0;
  int sel = 0;
  buf[0][tid] = v;
  __syncthreads();
#pragma unroll
  for (int off = 1; off < SCAN_BS; off <<= 1) {
    int s = buf[sel][tid];
    if (tid >= off) s += buf[sel][tid - off];
    buf[sel ^ 1][tid] = s;
    sel ^= 1;
    __syncthreads();
  }
  int incl = buf[sel][tid];
  if (tid < SCAN_NB) partials[tid] = incl - v;
  if (tid == SCAN_BS - 1) row_ptr[NN] = incl;
}

__global__ __launch_bounds__(SCAN_BS) void scan3_kernel(
    const int* __restrict__ escan, const int* __restrict__ partials,
    int* __restrict__ row_ptr, int* __restrict__ cursor) {
  const int i = blockIdx.x * SCAN_BS + threadIdx.x;
  if (i >= NN) return;
  int r = escan[i] + partials[blockIdx.x];
  row_ptr[i] = r;
  cursor[i] = r;
}

// ---------------------------------------------------------------------------
// Per-timestep fused kernel (R7 geometry: 8 lanes/node, KPRE=6, predicated).
// R11 changes: 4B CSR {u16 src, bf16 w}; v_old comes from out_{t-1}
// (L2-resident) instead of a dedicated fp32 state buffer; out store is a
// normal (cached) store since it's re-read next step; x stays nontemporal.
// ---------------------------------------------------------------------------
__global__ __launch_bounds__(256) void step1_kernel(
    const int* __restrict__ row_ptr,
    const unsigned int* __restrict__ csr,
    const ushort* __restrict__ r_old,   // bf16 relu state, node-major (N,8)
    ushort* __restrict__ r_new,
    const float* __restrict__ x_t,      // x + t*NN; batch stride TN
    const float* __restrict__ vprev,    // out + (t-1)*NN; batch stride TN
    const float* __restrict__ bias,
    const float* __restrict__ alpha,
    float* __restrict__ out_t,          // out + t*NN; batch stride TN
    int first) {
  int gid = blockIdx.x * blockDim.x + threadIdx.x;
  int node = gid >> 3;
  int lane = gid & 7;
  if (node >= NN) return;

  int e0 = row_ptr[node];
  int e1 = row_ptr[node + 1];
  int mybase = e0 + lane;
  int rem = e1 - mybase;
  int cnt = rem > 0 ? ((rem + LPN - 1) >> 3) : 0;   // my edge count (stride 8)

  // node-state loads independent of the edge chain — issue early
  float a = alpha[node];
  float bs = bias[node];
  size_t idx = (size_t)node * NB + lane;
  size_t boff = (size_t)lane * TN + node;
  float xv = __builtin_nontemporal_load(&x_t[boff]);
  float v = bs;
  if (!first) v = vprev[boff];

  // prefetch CSR entries (independent, exec-masked per slot); 4B each
  int soff[KPRE];
  float wk[KPRE];
#pragma unroll
  for (int k = 0; k < KPRE; ++k) {
    unsigned int c = (k < cnt) ? csr[mybase + (k << 3)] : 0u;
    soff[k] = (int)(c & 0xFFFFu) << 4;          // byte offset into 16B r rows
    wk[k] = __uint_as_float(c & 0xFFFF0000u);   // bf16 weight in high half
  }

  // predicated independent gathers: inactive slots issue NO memory request
  uint4 rv[KPRE];
#pragma unroll
  for (int k = 0; k < KPRE; ++k) {
    if (k < cnt)
      rv[k] = *(const uint4*)((const char*)r_old + soff[k]);
    else
      rv[k] = make_uint4(0, 0, 0, 0);
  }

  float acc[NB];
#pragma unroll
  for (int j = 0; j < NB; ++j) acc[j] = 0.f;

#pragma unroll
  for (int k = 0; k < KPRE; ++k) {
    float w = wk[k];
    acc[0] += w * __uint_as_float(rv[k].x << 16);
    acc[1] += w * __uint_as_float(rv[k].x & 0xffff0000u);
    acc[2] += w * __uint_as_float(rv[k].y << 16);
    acc[3] += w * __uint_as_float(rv[k].y & 0xffff0000u);
    acc[4] += w * __uint_as_float(rv[k].z << 16);
    acc[5] += w * __uint_as_float(rv[k].z & 0xffff0000u);
    acc[6] += w * __uint_as_float(rv[k].w << 16);
    acc[7] += w * __uint_as_float(rv[k].w & 0xffff0000u);
  }

  // overflow edges (deg > 48; ~0.3% of nodes)
  for (int e = mybase + (KPRE << 3); e < e1; e += LPN) {
    unsigned int c = csr[e];
    uint4 r8 = *(const uint4*)((const char*)r_old + ((size_t)(c & 0xFFFFu) << 4));
    float w = __uint_as_float(c & 0xFFFF0000u);
    acc[0] += w * __uint_as_float(r8.x << 16);
    acc[1] += w * __uint_as_float(r8.x & 0xffff0000u);
    acc[2] += w * __uint_as_float(r8.y << 16);
    acc[3] += w * __uint_as_float(r8.y & 0xffff0000u);
    acc[4] += w * __uint_as_float(r8.z << 16);
    acc[5] += w * __uint_as_float(r8.z & 0xffff0000u);
    acc[6] += w * __uint_as_float(r8.w << 16);
    acc[7] += w * __uint_as_float(r8.w & 0xffff0000u);
  }

  // butterfly reduce across the 8-lane group; lane l ends with valid acc[l]
#pragma unroll
  for (int off = 4; off; off >>= 1) {
#pragma unroll
    for (int j = 0; j < NB; ++j) {
      float t = __shfl_xor(acc[j], off);
      acc[j] = (((lane ^ j) & off) == 0) ? acc[j] + t : acc[j];
    }
  }
  float r = acc[0];
#pragma unroll
  for (int j = 1; j < NB; ++j) r = (lane == j) ? acc[j] : r;

  float vn = v + a * (bs - v + r + xv);
  __hip_bfloat16 rh = __float2bfloat16(fmaxf(vn, 0.f));
  r_new[idx] = *(ushort*)&rh;
  out_t[boff] = vn;   // cached store: re-read as vprev next step
}

// ---------------------------------------------------------------------------

extern "C" void kernel_launch(void* const* d_in, const int* in_sizes, int n_in,
                              void* d_out, int out_size, void* d_ws, size_t ws_size,
                              hipStream_t stream) {
  const float* x        = (const float*)d_in[0];
  const float* bias     = (const float*)d_in[1];
  const float* tc       = (const float*)d_in[2];
  const float* sgn      = (const float*)d_in[3];
  const float* syn_cnt  = (const float*)d_in[4];
  const float* syn_str  = (const float*)d_in[5];
  const int*   src      = (const int*)d_in[6];
  const int*   tgt      = (const int*)d_in[7];
  float* out = (float*)d_out;

  char* p = (char*)d_ws;
  auto take = [&p](size_t bytes) {
    char* r = p;
    p += (bytes + 255) & ~(size_t)255;
    return (void*)r;
  };
  ushort* r_a      = (ushort*)take((size_t)NN * NB * sizeof(ushort));
  ushort* r_b      = (ushort*)take((size_t)NN * NB * sizeof(ushort));
  float*  alpha    = (float*)take((size_t)NN * sizeof(float));
  int*    row_ptr  = (int*)take(((size_t)NN + 1) * sizeof(int));
  int*    cnt      = (int*)take((size_t)NN * sizeof(int));
  int*    cursor   = (int*)take((size_t)NN * sizeof(int));
  int*    escan    = (int*)take((size_t)NN * sizeof(int));
  int*    partials = (int*)take((size_t)SCAN_NB * sizeof(int));
  int*    bcur     = (int*)take((size_t)NBKT_PAD * sizeof(int));
  unsigned int* csr = (unsigned int*)take((size_t)NE * sizeof(unsigned int));
  unsigned long long* bkt =
      (unsigned long long*)take((size_t)NBKT * BKT_CAP * sizeof(unsigned long long));
  const bool use_bucketed = ((size_t)(p - (char*)d_ws) <= ws_size);

  init_nodes_kernel<<<(NN + 255) / 256, 256, 0, stream>>>(bias, tc, r_a,
                                                          alpha, cnt, bcur);
  if (use_bucketed) {
    fillA_kernel<<<(NE + ACHUNK - 1) / ACHUNK, 256, 0, stream>>>(
        src, tgt, sgn, syn_cnt, syn_str, cnt, bcur, bkt);
    scan1_kernel<<<SCAN_NB, SCAN_BS, 0, stream>>>(cnt, escan, partials);
    scan2_kernel<<<1, SCAN_BS, 0, stream>>>(partials, row_ptr);
    scan3_kernel<<<SCAN_NB, SCAN_BS, 0, stream>>>(escan, partials, row_ptr, cursor);
    fillB_kernel<<<NBKT_PAD * BPB, 256, 0, stream>>>(bkt, bcur, cursor, csr);
  } else {
    hist_kernel<<<(NE + 255) / 256, 256, 0, stream>>>(tgt, cnt);
    scan1_kernel<<<SCAN_NB, SCAN_BS, 0, stream>>>(cnt, escan, partials);
    scan2_kernel<<<1, SCAN_BS, 0, stream>>>(partials, row_ptr);
    scan3_kernel<<<SCAN_NB, SCAN_BS, 0, stream>>>(escan, partials, row_ptr, cursor);
    fill_kernel<<<(NE + 255) / 256, 256, 0, stream>>>(src, tgt, sgn, syn_cnt,
                                                      syn_str, cursor, csr);
  }

  // Sequential Euler steps; 8 lanes/node, 400K threads, plain launches.
  // v state lives in `out` itself (step t reads out_{t-1}).
  const int blocks = (NN * LPN + 255) / 256;
  const ushort* rin = r_a;
  ushort* rout = r_b;
  for (int t = 0; t < NT; ++t) {
    step1_kernel<<<blocks, 256, 0, stream>>>(
        row_ptr, csr, rin, rout,
        x + (size_t)t * NN,
        out + (size_t)(t > 0 ? t - 1 : 0) * NN,
        bias, alpha,
        out + (size_t)t * NN,
        t == 0 ? 1 : 0);
    ushort* tr = (ushort*)rin; rin = rout; rout = tr;
  }
}

// Round 12
// 1113.206 us; speedup vs baseline: 1.1543x; 1.0085x over previous
//
#include <hip/hip_runtime.h>
#include <hip/hip_bf16.h>

// Problem constants (Network_29197187678952)
#define NN 50000          // nodes
#define NE 1600000        // edges
#define NB 8              // batch
#define NT 80             // timesteps
#define TN ((size_t)NT * NN)   // stride between batches in x/out: 4,000,000
#define DT_F 0.02f

#define LPN 8             // lanes (threads) per node
#define KP 6              // padded edge slots per lane (deg <= 48, ~99.7%)
#define NN8 (NN * NB)     // thread slots: 400,000

// Bucketed CSR build
#define BKT_SHIFT 11
#define NBKT 25                         // ceil(50000 / 2048)
#define NBKT_PAD 32                     // mod-8-aligned for XCD pinning
#define BKT_CAP 68000                   // mean 65.5K, sigma ~255 -> ~10 sigma
#define ACHUNK 2048                     // edges staged per block in fillA
#define BPB 64                          // blocks per bucket in fillB

// ---------------------------------------------------------------------------
// Setup kernels (rebuilt every call).
// ---------------------------------------------------------------------------

__global__ void init_nodes_kernel(const float* __restrict__ bias,
                                  const float* __restrict__ tc,
                                  ushort* __restrict__ r0,
                                  float2* __restrict__ ab,
                                  int* __restrict__ cnt,
                                  int* __restrict__ bucket_cursor) {
  int n = blockIdx.x * blockDim.x + threadIdx.x;
  if (n >= NN) return;
  float b = bias[n];
  __hip_bfloat16 rb = __float2bfloat16(fmaxf(b, 0.f));
  ushort rbu = *(ushort*)&rb;
#pragma unroll
  for (int j = 0; j < NB; ++j) r0[(size_t)n * NB + j] = rbu;
  ab[n] = make_float2(DT_F / fmaxf(tc[n], DT_F), b);
  cnt[n] = 0;
  if (n < NBKT_PAD) bucket_cursor[n] = 0;
}

// ---- fallback path kernels (used only if ws_size too small for bkt) ----
__global__ void hist_kernel(const int* __restrict__ tgt, int* __restrict__ cnt) {
  int e = blockIdx.x * blockDim.x + threadIdx.x;
  if (e >= NE) return;
  atomicAdd(&cnt[tgt[e]], 1);
}

__global__ void fill_kernel(const int* __restrict__ src, const int* __restrict__ tgt,
                            const float* __restrict__ sgn, const float* __restrict__ syn_cnt,
                            const float* __restrict__ syn_str,
                            const int* __restrict__ row_ptr,
                            int* __restrict__ cursor0,
                            unsigned int* __restrict__ csrt,
                            unsigned int* __restrict__ ovf) {
  int e = blockIdx.x * blockDim.x + threadIdx.x;
  if (e >= NE) return;
  int t = tgt[e];
  float w = sgn[e] * syn_cnt[e] * fmaxf(syn_str[e], 0.f);
  __hip_bfloat16 wh = __float2bfloat16(w);
  unsigned int entry = (unsigned int)src[e] | ((unsigned int)*(ushort*)&wh << 16);
  int j = atomicAdd(&cursor0[t], 1);
  if (j < 48)
    csrt[(size_t)(j >> 3) * NN8 + t * 8 + (j & 7)] = entry;
  else
    ovf[row_ptr[t] + j] = entry;
}

// ---- fillA: bucketize edges by target-range + fused node histogram ----
__global__ __launch_bounds__(256) void fillA_kernel(
    const int* __restrict__ src, const int* __restrict__ tgt,
    const float* __restrict__ sgn, const float* __restrict__ syn_cnt,
    const float* __restrict__ syn_str,
    int* __restrict__ node_cnt,
    int* __restrict__ bucket_cursor,
    unsigned long long* __restrict__ bkt) {
  __shared__ int bcnt[NBKT];
  __shared__ int bbase[NBKT];
  __shared__ int bpos[NBKT + 1];
  __shared__ unsigned long long stage[ACHUNK];
  __shared__ unsigned char stageb[ACHUNK];

  const int tid = threadIdx.x;
  const int base = blockIdx.x * ACHUNK;
#define EPT (ACHUNK / 256)

  int b_[EPT], off_[EPT];
  unsigned long long ent_[EPT];
  bool val_[EPT];
#pragma unroll
  for (int k = 0; k < EPT; ++k) {
    int e = base + k * 256 + tid;
    val_[k] = e < NE;
    b_[k] = 0;
    ent_[k] = 0;
    if (val_[k]) {
      int s = src[e];
      int t = tgt[e];
      float w = sgn[e] * syn_cnt[e] * fmaxf(syn_str[e], 0.f);
      atomicAdd(&node_cnt[t], 1);
      b_[k] = t >> BKT_SHIFT;
      unsigned int packed = (unsigned int)s | ((unsigned int)(t & ((1 << BKT_SHIFT) - 1)) << 16);
      ent_[k] = ((unsigned long long)(unsigned int)__float_as_int(w) << 32) | packed;
    }
  }

  if (tid < NBKT) bcnt[tid] = 0;
  __syncthreads();
#pragma unroll
  for (int k = 0; k < EPT; ++k)
    if (val_[k]) off_[k] = atomicAdd(&bcnt[b_[k]], 1);
  __syncthreads();
  if (tid == 0) {
    int run = 0;
    for (int i = 0; i < NBKT; ++i) { bpos[i] = run; run += bcnt[i]; }
    bpos[NBKT] = run;
  }
  __syncthreads();
  if (tid < NBKT) bbase[tid] = atomicAdd(&bucket_cursor[tid], bcnt[tid]);
#pragma unroll
  for (int k = 0; k < EPT; ++k) {
    if (val_[k]) {
      int slot = bpos[b_[k]] + off_[k];
      stage[slot] = ent_[k];
      stageb[slot] = (unsigned char)b_[k];
    }
  }
  __syncthreads();
  const int tot = bpos[NBKT];
  for (int i = tid; i < tot; i += 256) {
    int bb = stageb[i];
    int dst = bbase[bb] + (i - bpos[bb]);
    if (dst < BKT_CAP)
      bkt[(size_t)bb * BKT_CAP + dst] = stage[i];
  }
#undef EPT
}

// ---- fillB: scatter bucket entries into padded-transposed CSR ----
__global__ __launch_bounds__(256) void fillB_kernel(
    const unsigned long long* __restrict__ bkt,
    const int* __restrict__ bucket_cursor,
    const int* __restrict__ row_ptr,
    int* __restrict__ cursor0,
    unsigned int* __restrict__ csrt,
    unsigned int* __restrict__ ovf) {
  const int b = blockIdx.x & (NBKT_PAD - 1);
  if (b >= NBKT) return;
  const int j = blockIdx.x >> 5;
  const int count = min(bucket_cursor[b], BKT_CAP);
  const unsigned long long* mybkt = bkt + (size_t)b * BKT_CAP;
  for (int i = j * 256 + threadIdx.x; i < count; i += BPB * 256) {
    unsigned long long ent = mybkt[i];
    unsigned int packed = (unsigned int)ent;
    float w = __int_as_float((int)(ent >> 32));
    unsigned int s = packed & 0xFFFF;
    int t = (b << BKT_SHIFT) + ((packed >> 16) & ((1 << BKT_SHIFT) - 1));
    __hip_bfloat16 wh = __float2bfloat16(w);
    unsigned int entry = s | ((unsigned int)*(ushort*)&wh << 16);
    int jj = atomicAdd(&cursor0[t], 1);
    if (jj < 48)
      csrt[(size_t)(jj >> 3) * NN8 + t * 8 + (jj & 7)] = entry;
    else
      ovf[row_ptr[t] + jj] = entry;
  }
}

// --- hierarchical 3-phase scan over NN counts ---
#define SCAN_BS 256
#define SCAN_NB ((NN + SCAN_BS - 1) / SCAN_BS)   // 196 blocks

__global__ __launch_bounds__(SCAN_BS) void scan1_kernel(
    const int* __restrict__ cnt, int* __restrict__ escan,
    int* __restrict__ partials) {
  __shared__ int buf[2][SCAN_BS];
  const int tid = threadIdx.x;
  const int i = blockIdx.x * SCAN_BS + tid;
  int v = (i < NN) ? cnt[i] : 0;
  int sel = 0;
  buf[0][tid] = v;
  __syncthreads();
#pragma unroll
  for (int off = 1; off < SCAN_BS; off <<= 1) {
    int s = buf[sel][tid];
    if (tid >= off) s += buf[sel][tid - off];
    buf[sel ^ 1][tid] = s;
    sel ^= 1;
    __syncthreads();
  }
  int incl = buf[sel][tid];
  if (i < NN) escan[i] = incl - v;
  if (tid == SCAN_BS - 1) partials[blockIdx.x] = incl;
}

__global__ __launch_bounds__(SCAN_BS) void scan2_kernel(
    int* __restrict__ partials, int* __restrict__ row_ptr) {
  __shared__ int buf[2][SCAN_BS];
  const int tid = threadIdx.x;
  int v = (tid < SCAN_NB) ? partials[tid] : 0;
  int sel = 0;
  buf[0][tid] = v;
  __syncthreads();
#pragma unroll
  for (int off = 1; off < SCAN_BS; off <<= 1) {
    int s = buf[sel][tid];
    if (tid >= off) s += buf[sel][tid - off];
    buf[sel ^ 1][tid] = s;
    sel ^= 1;
    __syncthreads();
  }
  int incl = buf[sel][tid];
  if (tid < SCAN_NB) partials[tid] = incl - v;
  if (tid == SCAN_BS - 1) row_ptr[NN] = incl;
}

// Phase 3: row_ptr, cursor0=0, and per-lane count bytes (cnt8).
__global__ __launch_bounds__(SCAN_BS) void scan3_kernel(
    const int* __restrict__ escan, const int* __restrict__ partials,
    const int* __restrict__ cnt,
    int* __restrict__ row_ptr, int* __restrict__ cursor0,
    unsigned long long* __restrict__ cnt8) {
  const int i = blockIdx.x * SCAN_BS + threadIdx.x;
  if (i >= NN) return;
  row_ptr[i] = escan[i] + partials[blockIdx.x];
  cursor0[i] = 0;
  int deg = cnt[i];
  unsigned long long packed;
  if (deg > 48) {
    packed = 0xFFFFFFFFFFFFFFFFull;           // sentinel: all lanes overflow-aware
  } else {
    packed = 0;
#pragma unroll
    for (int l = 0; l < 8; ++l) {
      int c = (deg - l + 7) >> 3;             // ceil((deg-l)/8), <=6 since deg<=48
      if (c < 0) c = 0;
      packed |= (unsigned long long)(unsigned int)c << (8 * l);
    }
  }
  cnt8[i] = packed;
}

// ---------------------------------------------------------------------------
// Per-timestep fused kernel. 8 lanes/node. R12: padded thread-slot CSR —
// csr-load addresses depend only on gid (no row_ptr hop); per-lane counts
// from cnt8 bytes; alpha+bias one float2. Dependent chain: csrt -> gather.
// ---------------------------------------------------------------------------
__global__ __launch_bounds__(256) void step1_kernel(
    const unsigned char* __restrict__ cnt8,
    const unsigned int* __restrict__ csrt,   // [KP][NN8] padded transposed
    const unsigned int* __restrict__ ovf,    // overflow CSR (row_ptr-indexed)
    const int* __restrict__ row_ptr,
    const ushort* __restrict__ r_old,        // bf16 relu state, (N,8)
    ushort* __restrict__ r_new,
    const float* __restrict__ x_t,           // x + t*NN; batch stride TN
    const float* __restrict__ vprev,         // out + (t-1)*NN
    const float2* __restrict__ ab,           // {alpha, bias}
    float* __restrict__ out_t,
    int first) {
  int gid = blockIdx.x * blockDim.x + threadIdx.x;
  int node = gid >> 3;
  int lane = gid & 7;
  if (node >= NN) return;

  // all early loads are gid/node-based: fully independent, issue together
  unsigned char c8 = cnt8[gid];
  float2 abv = ab[node];
  size_t boff = (size_t)lane * TN + node;
  float xv = __builtin_nontemporal_load(&x_t[boff]);
  float v = abv.y;
  if (!first) v = vprev[boff];

  unsigned int ce[KP];
#pragma unroll
  for (int k = 0; k < KP; ++k)
    ce[k] = csrt[(size_t)k * NN8 + gid];     // coalesced 256B/wave per plane

  int cnt = (c8 == 255u) ? KP : (int)c8;

  // predicated independent gathers (inactive slots: no memory request)
  uint4 rv[KP];
#pragma unroll
  for (int k = 0; k < KP; ++k) {
    if (k < cnt)
      rv[k] = *(const uint4*)((const char*)r_old + ((size_t)(ce[k] & 0xFFFFu) << 4));
    else
      rv[k] = make_uint4(0, 0, 0, 0);
  }

  float acc[NB];
#pragma unroll
  for (int j = 0; j < NB; ++j) acc[j] = 0.f;

#pragma unroll
  for (int k = 0; k < KP; ++k) {
    float w = __uint_as_float(ce[k] & 0xFFFF0000u);   // bf16 weight (0 in padding)
    acc[0] += w * __uint_as_float(rv[k].x << 16);
    acc[1] += w * __uint_as_float(rv[k].x & 0xffff0000u);
    acc[2] += w * __uint_as_float(rv[k].y << 16);
    acc[3] += w * __uint_as_float(rv[k].y & 0xffff0000u);
    acc[4] += w * __uint_as_float(rv[k].z << 16);
    acc[5] += w * __uint_as_float(rv[k].z & 0xffff0000u);
    acc[6] += w * __uint_as_float(rv[k].w << 16);
    acc[7] += w * __uint_as_float(rv[k].w & 0xffff0000u);
  }

  // overflow edges (deg > 48; ~0.3% of nodes pay the row_ptr hop)
  if (c8 == 255u) {
    int e0 = row_ptr[node];
    int e1 = row_ptr[node + 1];
    for (int e = e0 + 48 + lane; e < e1; e += LPN) {
      unsigned int c = ovf[e];
      uint4 r8 = *(const uint4*)((const char*)r_old + ((size_t)(c & 0xFFFFu) << 4));
      float w = __uint_as_float(c & 0xFFFF0000u);
      acc[0] += w * __uint_as_float(r8.x << 16);
      acc[1] += w * __uint_as_float(r8.x & 0xffff0000u);
      acc[2] += w * __uint_as_float(r8.y << 16);
      acc[3] += w * __uint_as_float(r8.y & 0xffff0000u);
      acc[4] += w * __uint_as_float(r8.z << 16);
      acc[5] += w * __uint_as_float(r8.z & 0xffff0000u);
      acc[6] += w * __uint_as_float(r8.w << 16);
      acc[7] += w * __uint_as_float(r8.w & 0xffff0000u);
    }
  }

  // butterfly reduce across the 8-lane group; lane l ends with valid acc[l]
#pragma unroll
  for (int off = 4; off; off >>= 1) {
#pragma unroll
    for (int j = 0; j < NB; ++j) {
      float t = __shfl_xor(acc[j], off);
      acc[j] = (((lane ^ j) & off) == 0) ? acc[j] + t : acc[j];
    }
  }
  float r = acc[0];
#pragma unroll
  for (int j = 1; j < NB; ++j) r = (lane == j) ? acc[j] : r;

  float vn = v + abv.x * (abv.y - v + r + xv);
  __hip_bfloat16 rh = __float2bfloat16(fmaxf(vn, 0.f));
  r_new[(size_t)node * NB + lane] = *(ushort*)&rh;
  out_t[boff] = vn;   // cached: re-read as vprev next step
}

// ---------------------------------------------------------------------------

extern "C" void kernel_launch(void* const* d_in, const int* in_sizes, int n_in,
                              void* d_out, int out_size, void* d_ws, size_t ws_size,
                              hipStream_t stream) {
  const float* x        = (const float*)d_in[0];
  const float* bias     = (const float*)d_in[1];
  const float* tc       = (const float*)d_in[2];
  const float* sgn      = (const float*)d_in[3];
  const float* syn_cnt  = (const float*)d_in[4];
  const float* syn_str  = (const float*)d_in[5];
  const int*   src      = (const int*)d_in[6];
  const int*   tgt      = (const int*)d_in[7];
  float* out = (float*)d_out;

  char* p = (char*)d_ws;
  auto take = [&p](size_t bytes) {
    char* r = p;
    p += (bytes + 255) & ~(size_t)255;
    return (void*)r;
  };
  ushort* r_a      = (ushort*)take((size_t)NN * NB * sizeof(ushort));
  ushort* r_b      = (ushort*)take((size_t)NN * NB * sizeof(ushort));
  float2* ab       = (float2*)take((size_t)NN * sizeof(float2));
  int*    row_ptr  = (int*)take(((size_t)NN + 1) * sizeof(int));
  int*    cnt      = (int*)take((size_t)NN * sizeof(int));
  int*    cursor0  = (int*)take((size_t)NN * sizeof(int));
  int*    escan    = (int*)take((size_t)NN * sizeof(int));
  int*    partials = (int*)take((size_t)SCAN_NB * sizeof(int));
  int*    bcur     = (int*)take((size_t)NBKT_PAD * sizeof(int));
  unsigned long long* cnt8 =
      (unsigned long long*)take((size_t)NN * sizeof(unsigned long long));
  unsigned int* csrt = (unsigned int*)take((size_t)KP * NN8 * sizeof(unsigned int));
  unsigned int* ovf  = (unsigned int*)take((size_t)NE * sizeof(unsigned int));
  unsigned long long* bkt =
      (unsigned long long*)take((size_t)NBKT * BKT_CAP * sizeof(unsigned long long));
  const bool use_bucketed = ((size_t)(p - (char*)d_ws) <= ws_size);

  // zero padded CSR (padding slots must be w=0; read every step)
  hipMemsetAsync(csrt, 0, (size_t)KP * NN8 * sizeof(unsigned int), stream);

  init_nodes_kernel<<<(NN + 255) / 256, 256, 0, stream>>>(bias, tc, r_a, ab,
                                                          cnt, bcur);
  if (use_bucketed) {
    fillA_kernel<<<(NE + ACHUNK - 1) / ACHUNK, 256, 0, stream>>>(
        src, tgt, sgn, syn_cnt, syn_str, cnt, bcur, bkt);
    scan1_kernel<<<SCAN_NB, SCAN_BS, 0, stream>>>(cnt, escan, partials);
    scan2_kernel<<<1, SCAN_BS, 0, stream>>>(partials, row_ptr);
    scan3_kernel<<<SCAN_NB, SCAN_BS, 0, stream>>>(escan, partials, cnt,
                                                  row_ptr, cursor0, cnt8);
    fillB_kernel<<<NBKT_PAD * BPB, 256, 0, stream>>>(bkt, bcur, row_ptr,
                                                     cursor0, csrt, ovf);
  } else {
    hist_kernel<<<(NE + 255) / 256, 256, 0, stream>>>(tgt, cnt);
    scan1_kernel<<<SCAN_NB, SCAN_BS, 0, stream>>>(cnt, escan, partials);
    scan2_kernel<<<1, SCAN_BS, 0, stream>>>(partials, row_ptr);
    scan3_kernel<<<SCAN_NB, SCAN_BS, 0, stream>>>(escan, partials, cnt,
                                                  row_ptr, cursor0, cnt8);
    fill_kernel<<<(NE + 255) / 256, 256, 0, stream>>>(src, tgt, sgn, syn_cnt,
                                                      syn_str, row_ptr, cursor0,
                                                      csrt, ovf);
  }

  // Sequential Euler steps; 8 lanes/node, 400K threads, plain launches.
  const int blocks = (NN8 + 255) / 256;
  const ushort* rin = r_a;
  ushort* rout = r_b;
  for (int t = 0; t < NT; ++t) {
    step1_kernel<<<blocks, 256, 0, stream>>>(
        (const unsigned char*)cnt8, csrt, ovf, row_ptr, rin, rout,
        x + (size_t)t * NN,
        out + (size_t)(t > 0 ? t - 1 : 0) * NN,
        ab,
        out + (size_t)t * NN,
        t == 0 ? 1 : 0);
    ushort* tr = (ushort*)rin; rin = rout; rout = tr;
  }
}

// Round 13
// 1028.266 us; speedup vs baseline: 1.2497x; 1.0826x over previous
//
#include <hip/hip_runtime.h>
#include <hip/hip_bf16.h>

// Problem constants (Network_29197187678952)
#define NN 50000          // nodes
#define NE 1600000        // edges
#define NB 8              // batch
#define NT 80             // timesteps
#define TN ((size_t)NT * NN)   // stride between batches in x/out: 4,000,000
#define DT_F 0.02f

#define LPN 8             // lanes (threads) per node
#define KP 6              // padded edge slots per lane (deg <= 48, ~99.7%)
#define NN8 (NN * NB)     // thread slots: 400,000
#define OVF_SLOTS 32      // overflow slots per node (deg <= 80; P(>80) ~ 1e-13)

// Bucketed CSR build
#define BKT_SHIFT 11
#define NBKT 25                         // ceil(50000 / 2048)
#define NBKT_PAD 32                     // mod-8-aligned for XCD pinning
#define BKT_CAP 68000                   // mean 65.5K, sigma ~255 -> ~10 sigma
#define ACHUNK 2048                     // edges staged per block in fillA
#define BPB 64                          // blocks per bucket in fillB

// ---------------------------------------------------------------------------
// Setup kernels (rebuilt every call).
// ---------------------------------------------------------------------------

__global__ void init_nodes_kernel(const float* __restrict__ bias,
                                  const float* __restrict__ tc,
                                  ushort* __restrict__ r0,
                                  float2* __restrict__ ab,
                                  int* __restrict__ cursor0,
                                  int* __restrict__ bucket_cursor) {
  int n = blockIdx.x * blockDim.x + threadIdx.x;
  if (n >= NN) return;
  float b = bias[n];
  __hip_bfloat16 rb = __float2bfloat16(fmaxf(b, 0.f));
  ushort rbu = *(ushort*)&rb;
#pragma unroll
  for (int j = 0; j < NB; ++j) r0[(size_t)n * NB + j] = rbu;
  ab[n] = make_float2(DT_F / fmaxf(tc[n], DT_F), b);
  cursor0[n] = 0;
  if (n < NBKT_PAD) bucket_cursor[n] = 0;
}

// ---- fillA: bucketize edges by target-range (no histogram needed) ----
__global__ __launch_bounds__(256) void fillA_kernel(
    const int* __restrict__ src, const int* __restrict__ tgt,
    const float* __restrict__ sgn, const float* __restrict__ syn_cnt,
    const float* __restrict__ syn_str,
    int* __restrict__ bucket_cursor,
    unsigned long long* __restrict__ bkt) {
  __shared__ int bcnt[NBKT];
  __shared__ int bbase[NBKT];
  __shared__ int bpos[NBKT + 1];
  __shared__ unsigned long long stage[ACHUNK];
  __shared__ unsigned char stageb[ACHUNK];

  const int tid = threadIdx.x;
  const int base = blockIdx.x * ACHUNK;
#define EPT (ACHUNK / 256)

  int b_[EPT], off_[EPT];
  unsigned long long ent_[EPT];
  bool val_[EPT];
#pragma unroll
  for (int k = 0; k < EPT; ++k) {
    int e = base + k * 256 + tid;
    val_[k] = e < NE;
    b_[k] = 0;
    ent_[k] = 0;
    if (val_[k]) {
      int s = src[e];
      int t = tgt[e];
      float w = sgn[e] * syn_cnt[e] * fmaxf(syn_str[e], 0.f);
      b_[k] = t >> BKT_SHIFT;
      unsigned int packed = (unsigned int)s | ((unsigned int)(t & ((1 << BKT_SHIFT) - 1)) << 16);
      ent_[k] = ((unsigned long long)(unsigned int)__float_as_int(w) << 32) | packed;
    }
  }

  if (tid < NBKT) bcnt[tid] = 0;
  __syncthreads();
#pragma unroll
  for (int k = 0; k < EPT; ++k)
    if (val_[k]) off_[k] = atomicAdd(&bcnt[b_[k]], 1);
  __syncthreads();
  if (tid == 0) {
    int run = 0;
    for (int i = 0; i < NBKT; ++i) { bpos[i] = run; run += bcnt[i]; }
    bpos[NBKT] = run;
  }
  __syncthreads();
  if (tid < NBKT) bbase[tid] = atomicAdd(&bucket_cursor[tid], bcnt[tid]);
#pragma unroll
  for (int k = 0; k < EPT; ++k) {
    if (val_[k]) {
      int slot = bpos[b_[k]] + off_[k];
      stage[slot] = ent_[k];
      stageb[slot] = (unsigned char)b_[k];
    }
  }
  __syncthreads();
  const int tot = bpos[NBKT];
  for (int i = tid; i < tot; i += 256) {
    int bb = stageb[i];
    int dst = bbase[bb] + (i - bpos[bb]);
    if (dst < BKT_CAP)
      bkt[(size_t)bb * BKT_CAP + dst] = stage[i];
  }
#undef EPT
}

// ---- fillB: scatter bucket entries into padded CSR (bucket pinned per XCD) ----
__global__ __launch_bounds__(256) void fillB_kernel(
    const unsigned long long* __restrict__ bkt,
    const int* __restrict__ bucket_cursor,
    int* __restrict__ cursor0,
    unsigned int* __restrict__ csrt,
    unsigned int* __restrict__ ovf) {
  const int b = blockIdx.x & (NBKT_PAD - 1);
  if (b >= NBKT) return;
  const int j = blockIdx.x >> 5;
  const int count = min(bucket_cursor[b], BKT_CAP);
  const unsigned long long* mybkt = bkt + (size_t)b * BKT_CAP;
  for (int i = j * 256 + threadIdx.x; i < count; i += BPB * 256) {
    unsigned long long ent = mybkt[i];
    unsigned int packed = (unsigned int)ent;
    float w = __int_as_float((int)(ent >> 32));
    unsigned int s = packed & 0xFFFF;
    int t = (b << BKT_SHIFT) + ((packed >> 16) & ((1 << BKT_SHIFT) - 1));
    __hip_bfloat16 wh = __float2bfloat16(w);
    unsigned int entry = s | ((unsigned int)*(ushort*)&wh << 16);
    int jj = atomicAdd(&cursor0[t], 1);
    if (jj < 48) {
      csrt[(size_t)(jj >> 3) * NN8 + t * 8 + (jj & 7)] = entry;
    } else {
      int o = jj - 48;
      if (o < OVF_SLOTS) ovf[(size_t)t * OVF_SLOTS + o] = entry;
    }
  }
}

// ---- fallback (ws too small for bkt): direct scatter ----
__global__ void fill_direct_kernel(const int* __restrict__ src, const int* __restrict__ tgt,
                                   const float* __restrict__ sgn, const float* __restrict__ syn_cnt,
                                   const float* __restrict__ syn_str,
                                   int* __restrict__ cursor0,
                                   unsigned int* __restrict__ csrt,
                                   unsigned int* __restrict__ ovf) {
  int e = blockIdx.x * blockDim.x + threadIdx.x;
  if (e >= NE) return;
  int t = tgt[e];
  float w = sgn[e] * syn_cnt[e] * fmaxf(syn_str[e], 0.f);
  __hip_bfloat16 wh = __float2bfloat16(w);
  unsigned int entry = (unsigned int)src[e] | ((unsigned int)*(ushort*)&wh << 16);
  int j = atomicAdd(&cursor0[t], 1);
  if (j < 48) {
    csrt[(size_t)(j >> 3) * NN8 + t * 8 + (j & 7)] = entry;
  } else {
    int o = j - 48;
    if (o < OVF_SLOTS) ovf[(size_t)t * OVF_SLOTS + o] = entry;
  }
}

// ---- cnt8: per-lane slot counts from final degrees (after fill) ----
__global__ __launch_bounds__(256) void cnt8_kernel(const int* __restrict__ deg,
                                                   unsigned long long* __restrict__ cnt8) {
  int i = blockIdx.x * blockDim.x + threadIdx.x;
  if (i >= NN) return;
  int d = deg[i];
  unsigned long long packed;
  if (d > 48) {
    packed = 0xFFFFFFFFFFFFFFFFull;          // sentinel: lanes take overflow path
  } else {
    packed = 0;
#pragma unroll
    for (int l = 0; l < 8; ++l) {
      int c = (d - l + 7) >> 3;              // ceil((d-l)/8), <=6
      if (c < 0) c = 0;
      packed |= (unsigned long long)(unsigned int)c << (8 * l);
    }
  }
  cnt8[i] = packed;
}

// ---------------------------------------------------------------------------
// Per-timestep fused kernel. 8 lanes/node, padded thread-slot CSR.
// R13: r_new stored NON-TEMPORAL -> lands clean in L3, so next step's
// cross-XCD gathers avoid the dirty-L2 snoop/writeback path. out_t stays
// cached (re-read next step by the same thread -> same XCD L2).
// ---------------------------------------------------------------------------
__global__ __launch_bounds__(256) void step1_kernel(
    const unsigned char* __restrict__ cnt8,
    const unsigned int* __restrict__ csrt,   // [KP][NN8] padded transposed
    const unsigned int* __restrict__ ovf,    // [NN][OVF_SLOTS]
    const int* __restrict__ deg,             // final per-node degree
    const ushort* __restrict__ r_old,        // bf16 relu state, (N,8)
    ushort* __restrict__ r_new,
    const float* __restrict__ x_t,           // x + t*NN; batch stride TN
    const float* __restrict__ vprev,         // out + (t-1)*NN
    const float2* __restrict__ ab,           // {alpha, bias}
    float* __restrict__ out_t,
    int first) {
  int gid = blockIdx.x * blockDim.x + threadIdx.x;
  int node = gid >> 3;
  int lane = gid & 7;
  if (node >= NN) return;

  // all early loads are gid/node-based: fully independent, issue together
  unsigned char c8 = cnt8[gid];
  float2 abv = ab[node];
  size_t boff = (size_t)lane * TN + node;
  float xv = __builtin_nontemporal_load(&x_t[boff]);
  float v = abv.y;
  if (!first) v = vprev[boff];

  unsigned int ce[KP];
#pragma unroll
  for (int k = 0; k < KP; ++k)
    ce[k] = csrt[(size_t)k * NN8 + gid];     // coalesced 256B/wave per plane

  int cnt = (c8 == 255u) ? KP : (int)c8;

  // predicated independent gathers (inactive slots: no memory request)
  uint4 rv[KP];
#pragma unroll
  for (int k = 0; k < KP; ++k) {
    if (k < cnt)
      rv[k] = *(const uint4*)((const char*)r_old + ((size_t)(ce[k] & 0xFFFFu) << 4));
    else
      rv[k] = make_uint4(0, 0, 0, 0);
  }

  float acc[NB];
#pragma unroll
  for (int j = 0; j < NB; ++j) acc[j] = 0.f;

#pragma unroll
  for (int k = 0; k < KP; ++k) {
    float w = __uint_as_float(ce[k] & 0xFFFF0000u);   // bf16 weight (0 in padding)
    acc[0] += w * __uint_as_float(rv[k].x << 16);
    acc[1] += w * __uint_as_float(rv[k].x & 0xffff0000u);
    acc[2] += w * __uint_as_float(rv[k].y << 16);
    acc[3] += w * __uint_as_float(rv[k].y & 0xffff0000u);
    acc[4] += w * __uint_as_float(rv[k].z << 16);
    acc[5] += w * __uint_as_float(rv[k].z & 0xffff0000u);
    acc[6] += w * __uint_as_float(rv[k].w << 16);
    acc[7] += w * __uint_as_float(rv[k].w & 0xffff0000u);
  }

  // overflow edges (deg > 48; ~0.3% of nodes)
  if (c8 == 255u) {
    int d = deg[node];
    if (d > 48 + OVF_SLOTS) d = 48 + OVF_SLOTS;
    for (int e = 48 + lane; e < d; e += LPN) {
      unsigned int c = ovf[(size_t)node * OVF_SLOTS + (e - 48)];
      uint4 r8 = *(const uint4*)((const char*)r_old + ((size_t)(c & 0xFFFFu) << 4));
      float w = __uint_as_float(c & 0xFFFF0000u);
      acc[0] += w * __uint_as_float(r8.x << 16);
      acc[1] += w * __uint_as_float(r8.x & 0xffff0000u);
      acc[2] += w * __uint_as_float(r8.y << 16);
      acc[3] += w * __uint_as_float(r8.y & 0xffff0000u);
      acc[4] += w * __uint_as_float(r8.z << 16);
      acc[5] += w * __uint_as_float(r8.z & 0xffff0000u);
      acc[6] += w * __uint_as_float(r8.w << 16);
      acc[7] += w * __uint_as_float(r8.w & 0xffff0000u);
    }
  }

  // butterfly reduce across the 8-lane group; lane l ends with valid acc[l]
#pragma unroll
  for (int off = 4; off; off >>= 1) {
#pragma unroll
    for (int j = 0; j < NB; ++j) {
      float t = __shfl_xor(acc[j], off);
      acc[j] = (((lane ^ j) & off) == 0) ? acc[j] + t : acc[j];
    }
  }
  float r = acc[0];
#pragma unroll
  for (int j = 1; j < NB; ++j) r = (lane == j) ? acc[j] : r;

  float vn = v + abv.x * (abv.y - v + r + xv);
  __hip_bfloat16 rh = __float2bfloat16(fmaxf(vn, 0.f));
  ushort rhu = *(ushort*)&rh;
  __builtin_nontemporal_store(rhu, &r_new[(size_t)node * NB + lane]);
  out_t[boff] = vn;   // cached: re-read as vprev next step (same XCD)
}

// ---------------------------------------------------------------------------

extern "C" void kernel_launch(void* const* d_in, const int* in_sizes, int n_in,
                              void* d_out, int out_size, void* d_ws, size_t ws_size,
                              hipStream_t stream) {
  const float* x        = (const float*)d_in[0];
  const float* bias     = (const float*)d_in[1];
  const float* tc       = (const float*)d_in[2];
  const float* sgn      = (const float*)d_in[3];
  const float* syn_cnt  = (const float*)d_in[4];
  const float* syn_str  = (const float*)d_in[5];
  const int*   src      = (const int*)d_in[6];
  const int*   tgt      = (const int*)d_in[7];
  float* out = (float*)d_out;

  char* p = (char*)d_ws;
  auto take = [&p](size_t bytes) {
    char* r = p;
    p += (bytes + 255) & ~(size_t)255;
    return (void*)r;
  };
  ushort* r_a      = (ushort*)take((size_t)NN * NB * sizeof(ushort));
  ushort* r_b      = (ushort*)take((size_t)NN * NB * sizeof(ushort));
  float2* ab       = (float2*)take((size_t)NN * sizeof(float2));
  int*    cursor0  = (int*)take((size_t)NN * sizeof(int));
  int*    bcur     = (int*)take((size_t)NBKT_PAD * sizeof(int));
  unsigned long long* cnt8 =
      (unsigned long long*)take((size_t)NN * sizeof(unsigned long long));
  unsigned int* csrt = (unsigned int*)take((size_t)KP * NN8 * sizeof(unsigned int));
  unsigned int* ovf  = (unsigned int*)take((size_t)NN * OVF_SLOTS * sizeof(unsigned int));
  unsigned long long* bkt =
      (unsigned long long*)take((size_t)NBKT * BKT_CAP * sizeof(unsigned long long));
  const bool use_bucketed = ((size_t)(p - (char*)d_ws) <= ws_size);

  // zero padded CSR (padding slots must be w=0; read every step)
  hipMemsetAsync(csrt, 0, (size_t)KP * NN8 * sizeof(unsigned int), stream);

  init_nodes_kernel<<<(NN + 255) / 256, 256, 0, stream>>>(bias, tc, r_a, ab,
                                                          cursor0, bcur);
  if (use_bucketed) {
    fillA_kernel<<<(NE + ACHUNK - 1) / ACHUNK, 256, 0, stream>>>(
        src, tgt, sgn, syn_cnt, syn_str, bcur, bkt);
    fillB_kernel<<<NBKT_PAD * BPB, 256, 0, stream>>>(bkt, bcur, cursor0,
                                                     csrt, ovf);
  } else {
    fill_direct_kernel<<<(NE + 255) / 256, 256, 0, stream>>>(
        src, tgt, sgn, syn_cnt, syn_str, cursor0, csrt, ovf);
  }
  cnt8_kernel<<<(NN + 255) / 256, 256, 0, stream>>>(cursor0, cnt8);

  // Sequential Euler steps; 8 lanes/node, 400K threads, plain launches.
  const int blocks = (NN8 + 255) / 256;
  const ushort* rin = r_a;
  ushort* rout = r_b;
  for (int t = 0; t < NT; ++t) {
    step1_kernel<<<blocks, 256, 0, stream>>>(
        (const unsigned char*)cnt8, csrt, ovf, cursor0, rin, rout,
        x + (size_t)t * NN,
        out + (size_t)(t > 0 ? t - 1 : 0) * NN,
        ab,
        out + (size_t)t * NN,
        t == 0 ? 1 : 0);
    ushort* tr = (ushort*)rin; rin = rout; rout = tr;
  }
}

// Round 14
// 1000.599 us; speedup vs baseline: 1.2842x; 1.0277x over previous
//
#include <hip/hip_runtime.h>
#include <hip/hip_bf16.h>

// Problem constants (Network_29197187678952)
#define NN 50000          // nodes
#define NE 1600000        // edges
#define NB 8              // batch
#define NT 80             // timesteps
#define TN ((size_t)NT * NN)   // stride between batches in x/out: 4,000,000
#define DT_F 0.02f

#define LPN 8             // lanes (threads) per node
#define KP 6              // padded edge slots per lane (deg <= 48, ~99.7%)
#define NN8 (NN * NB)     // thread slots: 400,000
#define OVF_SLOTS 32      // overflow slots per node (deg <= 80; P(>80) ~ 1e-13)

// Bucketed CSR build
#define BKT_SHIFT 11
#define NBKT 25                         // ceil(50000 / 2048)
#define NBKT_PAD 32                     // mod-8-aligned for XCD pinning
#define BKT_CAP 68000                   // mean 65.5K, sigma ~255 -> ~10 sigma
#define ACHUNK 2048                     // edges staged per block in fillA
#define BPB 64                          // blocks per bucket in fillB

// ---------------------------------------------------------------------------
// Setup kernels (rebuilt every call).
// ---------------------------------------------------------------------------

__global__ void init_nodes_kernel(const float* __restrict__ bias,
                                  const float* __restrict__ tc,
                                  ushort* __restrict__ r0,
                                  float2* __restrict__ ab,
                                  int* __restrict__ cursor0,
                                  int* __restrict__ bucket_cursor) {
  int n = blockIdx.x * blockDim.x + threadIdx.x;
  if (n >= NN) return;
  float b = bias[n];
  __hip_bfloat16 rb = __float2bfloat16(fmaxf(b, 0.f));
  ushort rbu = *(ushort*)&rb;
#pragma unroll
  for (int j = 0; j < NB; ++j) r0[(size_t)n * NB + j] = rbu;
  ab[n] = make_float2(DT_F / fmaxf(tc[n], DT_F), b);
  cursor0[n] = 0;
  if (n < NBKT_PAD) bucket_cursor[n] = 0;
}

// ---- fillA: bucketize edges by target-range ----
__global__ __launch_bounds__(256) void fillA_kernel(
    const int* __restrict__ src, const int* __restrict__ tgt,
    const float* __restrict__ sgn, const float* __restrict__ syn_cnt,
    const float* __restrict__ syn_str,
    int* __restrict__ bucket_cursor,
    unsigned long long* __restrict__ bkt) {
  __shared__ int bcnt[NBKT];
  __shared__ int bbase[NBKT];
  __shared__ int bpos[NBKT + 1];
  __shared__ unsigned long long stage[ACHUNK];
  __shared__ unsigned char stageb[ACHUNK];

  const int tid = threadIdx.x;
  const int base = blockIdx.x * ACHUNK;
#define EPT (ACHUNK / 256)

  int b_[EPT], off_[EPT];
  unsigned long long ent_[EPT];
  bool val_[EPT];
#pragma unroll
  for (int k = 0; k < EPT; ++k) {
    int e = base + k * 256 + tid;
    val_[k] = e < NE;
    b_[k] = 0;
    ent_[k] = 0;
    if (val_[k]) {
      int s = src[e];
      int t = tgt[e];
      float w = sgn[e] * syn_cnt[e] * fmaxf(syn_str[e], 0.f);
      b_[k] = t >> BKT_SHIFT;
      unsigned int packed = (unsigned int)s | ((unsigned int)(t & ((1 << BKT_SHIFT) - 1)) << 16);
      ent_[k] = ((unsigned long long)(unsigned int)__float_as_int(w) << 32) | packed;
    }
  }

  if (tid < NBKT) bcnt[tid] = 0;
  __syncthreads();
#pragma unroll
  for (int k = 0; k < EPT; ++k)
    if (val_[k]) off_[k] = atomicAdd(&bcnt[b_[k]], 1);
  __syncthreads();
  if (tid == 0) {
    int run = 0;
    for (int i = 0; i < NBKT; ++i) { bpos[i] = run; run += bcnt[i]; }
    bpos[NBKT] = run;
  }
  __syncthreads();
  if (tid < NBKT) bbase[tid] = atomicAdd(&bucket_cursor[tid], bcnt[tid]);
#pragma unroll
  for (int k = 0; k < EPT; ++k) {
    if (val_[k]) {
      int slot = bpos[b_[k]] + off_[k];
      stage[slot] = ent_[k];
      stageb[slot] = (unsigned char)b_[k];
    }
  }
  __syncthreads();
  const int tot = bpos[NBKT];
  for (int i = tid; i < tot; i += 256) {
    int bb = stageb[i];
    int dst = bbase[bb] + (i - bpos[bb]);
    if (dst < BKT_CAP)
      bkt[(size_t)bb * BKT_CAP + dst] = stage[i];
  }
#undef EPT
}

// ---- fillB: scatter bucket entries into padded CSR (bucket pinned per XCD) ----
__global__ __launch_bounds__(256) void fillB_kernel(
    const unsigned long long* __restrict__ bkt,
    const int* __restrict__ bucket_cursor,
    int* __restrict__ cursor0,
    unsigned int* __restrict__ csrt,
    unsigned int* __restrict__ ovf) {
  const int b = blockIdx.x & (NBKT_PAD - 1);
  if (b >= NBKT) return;
  const int j = blockIdx.x >> 5;
  const int count = min(bucket_cursor[b], BKT_CAP);
  const unsigned long long* mybkt = bkt + (size_t)b * BKT_CAP;
  for (int i = j * 256 + threadIdx.x; i < count; i += BPB * 256) {
    unsigned long long ent = mybkt[i];
    unsigned int packed = (unsigned int)ent;
    float w = __int_as_float((int)(ent >> 32));
    unsigned int s = packed & 0xFFFF;
    int t = (b << BKT_SHIFT) + ((packed >> 16) & ((1 << BKT_SHIFT) - 1));
    __hip_bfloat16 wh = __float2bfloat16(w);
    unsigned int entry = s | ((unsigned int)*(ushort*)&wh << 16);
    int jj = atomicAdd(&cursor0[t], 1);
    if (jj < 48) {
      csrt[(size_t)(jj >> 3) * NN8 + t * 8 + (jj & 7)] = entry;
    } else {
      int o = jj - 48;
      if (o < OVF_SLOTS) ovf[(size_t)t * OVF_SLOTS + o] = entry;
    }
  }
}

// ---- fallback (ws too small for bkt): direct scatter ----
__global__ void fill_direct_kernel(const int* __restrict__ src, const int* __restrict__ tgt,
                                   const float* __restrict__ sgn, const float* __restrict__ syn_cnt,
                                   const float* __restrict__ syn_str,
                                   int* __restrict__ cursor0,
                                   unsigned int* __restrict__ csrt,
                                   unsigned int* __restrict__ ovf) {
  int e = blockIdx.x * blockDim.x + threadIdx.x;
  if (e >= NE) return;
  int t = tgt[e];
  float w = sgn[e] * syn_cnt[e] * fmaxf(syn_str[e], 0.f);
  __hip_bfloat16 wh = __float2bfloat16(w);
  unsigned int entry = (unsigned int)src[e] | ((unsigned int)*(ushort*)&wh << 16);
  int j = atomicAdd(&cursor0[t], 1);
  if (j < 48) {
    csrt[(size_t)(j >> 3) * NN8 + t * 8 + (j & 7)] = entry;
  } else {
    int o = j - 48;
    if (o < OVF_SLOTS) ovf[(size_t)t * OVF_SLOTS + o] = entry;
  }
}

// ---- cnt8: per-lane slot counts from final degrees (after fill) ----
__global__ __launch_bounds__(256) void cnt8_kernel(const int* __restrict__ deg,
                                                   unsigned long long* __restrict__ cnt8) {
  int i = blockIdx.x * blockDim.x + threadIdx.x;
  if (i >= NN) return;
  int d = deg[i];
  unsigned long long packed;
  if (d > 48) {
    packed = 0xFFFFFFFFFFFFFFFFull;          // sentinel: lanes take overflow path
  } else {
    packed = 0;
#pragma unroll
    for (int l = 0; l < 8; ++l) {
      int c = (d - l + 7) >> 3;              // ceil((d-l)/8), <=6
      if (c < 0) c = 0;
      packed |= (unsigned long long)(unsigned int)c << (8 * l);
    }
  }
  cnt8[i] = packed;
}

// ---------------------------------------------------------------------------
// Per-timestep fused kernel. 8 lanes/node, padded thread-slot CSR, NT r-store.
// R14: (1) weight guarded by (k<cnt) cndmask -> padding slots inert without
// any zero-init (csrt memset removed from the captured graph);
// (2) select-then-shfl reduce ladder: 7 shfl instead of 24.
// ---------------------------------------------------------------------------
__global__ __launch_bounds__(256) void step1_kernel(
    const unsigned char* __restrict__ cnt8,
    const unsigned int* __restrict__ csrt,   // [KP][NN8] padded transposed
    const unsigned int* __restrict__ ovf,    // [NN][OVF_SLOTS]
    const int* __restrict__ deg,             // final per-node degree
    const ushort* __restrict__ r_old,        // bf16 relu state, (N,8)
    ushort* __restrict__ r_new,
    const float* __restrict__ x_t,           // x + t*NN; batch stride TN
    const float* __restrict__ vprev,         // out + (t-1)*NN
    const float2* __restrict__ ab,           // {alpha, bias}
    float* __restrict__ out_t,
    int first) {
  int gid = blockIdx.x * blockDim.x + threadIdx.x;
  int node = gid >> 3;
  int lane = gid & 7;
  if (node >= NN) return;

  // all early loads are gid/node-based: fully independent, issue together
  unsigned char c8 = cnt8[gid];
  float2 abv = ab[node];
  size_t boff = (size_t)lane * TN + node;
  float xv = __builtin_nontemporal_load(&x_t[boff]);
  float v = abv.y;
  if (!first) v = vprev[boff];

  unsigned int ce[KP];
#pragma unroll
  for (int k = 0; k < KP; ++k)
    ce[k] = csrt[(size_t)k * NN8 + gid];     // coalesced 256B/wave per plane

  int cnt = (c8 == 255u) ? KP : (int)c8;

  // predicated independent gathers (inactive slots: no memory request)
  uint4 rv[KP];
#pragma unroll
  for (int k = 0; k < KP; ++k) {
    if (k < cnt)
      rv[k] = *(const uint4*)((const char*)r_old + ((size_t)(ce[k] & 0xFFFFu) << 4));
    else
      rv[k] = make_uint4(0, 0, 0, 0);
  }

  float acc[NB];
#pragma unroll
  for (int j = 0; j < NB; ++j) acc[j] = 0.f;

#pragma unroll
  for (int k = 0; k < KP; ++k) {
    // guard w so padding slots (garbage bits, never zero-initialized) are inert
    float w = (k < cnt) ? __uint_as_float(ce[k] & 0xFFFF0000u) : 0.f;
    acc[0] += w * __uint_as_float(rv[k].x << 16);
    acc[1] += w * __uint_as_float(rv[k].x & 0xffff0000u);
    acc[2] += w * __uint_as_float(rv[k].y << 16);
    acc[3] += w * __uint_as_float(rv[k].y & 0xffff0000u);
    acc[4] += w * __uint_as_float(rv[k].z << 16);
    acc[5] += w * __uint_as_float(rv[k].z & 0xffff0000u);
    acc[6] += w * __uint_as_float(rv[k].w << 16);
    acc[7] += w * __uint_as_float(rv[k].w & 0xffff0000u);
  }

  // overflow edges (deg > 48; ~0.3% of nodes)
  if (c8 == 255u) {
    int d = deg[node];
    if (d > 48 + OVF_SLOTS) d = 48 + OVF_SLOTS;
    for (int e = 48 + lane; e < d; e += LPN) {
      unsigned int c = ovf[(size_t)node * OVF_SLOTS + (e - 48)];
      uint4 r8 = *(const uint4*)((const char*)r_old + ((size_t)(c & 0xFFFFu) << 4));
      float w = __uint_as_float(c & 0xFFFF0000u);
      acc[0] += w * __uint_as_float(r8.x << 16);
      acc[1] += w * __uint_as_float(r8.x & 0xffff0000u);
      acc[2] += w * __uint_as_float(r8.y << 16);
      acc[3] += w * __uint_as_float(r8.y & 0xffff0000u);
      acc[4] += w * __uint_as_float(r8.z << 16);
      acc[5] += w * __uint_as_float(r8.z & 0xffff0000u);
      acc[6] += w * __uint_as_float(r8.w << 16);
      acc[7] += w * __uint_as_float(r8.w & 0xffff0000u);
    }
  }

  // select-then-shfl reduce ladder: lane l ends with batch-l sum (7 shfl).
  // stage 1 (xor 4): keep batches (lane&4)..(lane&4)+3 over lane-pair {l, l^4}
  const bool s4 = (lane & 4) != 0;
  float m0 = s4 ? acc[4] : acc[0], q0 = s4 ? acc[0] : acc[4];
  float m1 = s4 ? acc[5] : acc[1], q1 = s4 ? acc[1] : acc[5];
  float m2 = s4 ? acc[6] : acc[2], q2 = s4 ? acc[2] : acc[6];
  float m3 = s4 ? acc[7] : acc[3], q3 = s4 ? acc[3] : acc[7];
  float b0 = m0 + __shfl_xor(q0, 4);
  float b1 = m1 + __shfl_xor(q1, 4);
  float b2 = m2 + __shfl_xor(q2, 4);
  float b3 = m3 + __shfl_xor(q3, 4);
  // stage 2 (xor 2)
  const bool s2 = (lane & 2) != 0;
  float n0 = s2 ? b2 : b0, t0 = s2 ? b0 : b2;
  float n1 = s2 ? b3 : b1, t1 = s2 ? b1 : b3;
  float c0 = n0 + __shfl_xor(t0, 2);
  float c1 = n1 + __shfl_xor(t1, 2);
  // stage 3 (xor 1)
  const bool s1 = (lane & 1) != 0;
  float pp = s1 ? c1 : c0, qq = s1 ? c0 : c1;
  float r = pp + __shfl_xor(qq, 1);

  float vn = v + abv.x * (abv.y - v + r + xv);
  __hip_bfloat16 rh = __float2bfloat16(fmaxf(vn, 0.f));
  ushort rhu = *(ushort*)&rh;
  __builtin_nontemporal_store(rhu, &r_new[(size_t)node * NB + lane]);
  out_t[boff] = vn;   // cached: re-read as vprev next step (same XCD)
}

// ---------------------------------------------------------------------------

extern "C" void kernel_launch(void* const* d_in, const int* in_sizes, int n_in,
                              void* d_out, int out_size, void* d_ws, size_t ws_size,
                              hipStream_t stream) {
  const float* x        = (const float*)d_in[0];
  const float* bias     = (const float*)d_in[1];
  const float* tc       = (const float*)d_in[2];
  const float* sgn      = (const float*)d_in[3];
  const float* syn_cnt  = (const float*)d_in[4];
  const float* syn_str  = (const float*)d_in[5];
  const int*   src      = (const int*)d_in[6];
  const int*   tgt      = (const int*)d_in[7];
  float* out = (float*)d_out;

  char* p = (char*)d_ws;
  auto take = [&p](size_t bytes) {
    char* r = p;
    p += (bytes + 255) & ~(size_t)255;
    return (void*)r;
  };
  ushort* r_a      = (ushort*)take((size_t)NN * NB * sizeof(ushort));
  ushort* r_b      = (ushort*)take((size_t)NN * NB * sizeof(ushort));
  float2* ab       = (float2*)take((size_t)NN * sizeof(float2));
  int*    cursor0  = (int*)take((size_t)NN * sizeof(int));
  int*    bcur     = (int*)take((size_t)NBKT_PAD * sizeof(int));
  unsigned long long* cnt8 =
      (unsigned long long*)take((size_t)NN * sizeof(unsigned long long));
  unsigned int* csrt = (unsigned int*)take((size_t)KP * NN8 * sizeof(unsigned int));
  unsigned int* ovf  = (unsigned int*)take((size_t)NN * OVF_SLOTS * sizeof(unsigned int));
  unsigned long long* bkt =
      (unsigned long long*)take((size_t)NBKT * BKT_CAP * sizeof(unsigned long long));
  const bool use_bucketed = ((size_t)(p - (char*)d_ws) <= ws_size);

  // NOTE: no csrt memset — padding slots are inert via the (k<cnt) weight
  // guard in step1_kernel, so stale/poison bits are never multiplied in.

  init_nodes_kernel<<<(NN + 255) / 256, 256, 0, stream>>>(bias, tc, r_a, ab,
                                                          cursor0, bcur);
  if (use_bucketed) {
    fillA_kernel<<<(NE + ACHUNK - 1) / ACHUNK, 256, 0, stream>>>(
        src, tgt, sgn, syn_cnt, syn_str, bcur, bkt);
    fillB_kernel<<<NBKT_PAD * BPB, 256, 0, stream>>>(bkt, bcur, cursor0,
                                                     csrt, ovf);
  } else {
    fill_direct_kernel<<<(NE + 255) / 256, 256, 0, stream>>>(
        src, tgt, sgn, syn_cnt, syn_str, cursor0, csrt, ovf);
  }
  cnt8_kernel<<<(NN + 255) / 256, 256, 0, stream>>>(cursor0, cnt8);

  // Sequential Euler steps; 8 lanes/node, 400K threads, plain launches.
  const int blocks = (NN8 + 255) / 256;
  const ushort* rin = r_a;
  ushort* rout = r_b;
  for (int t = 0; t < NT; ++t) {
    step1_kernel<<<blocks, 256, 0, stream>>>(
        (const unsigned char*)cnt8, csrt, ovf, cursor0, rin, rout,
        x + (size_t)t * NN,
        out + (size_t)(t > 0 ? t - 1 : 0) * NN,
        ab,
        out + (size_t)t * NN,
        t == 0 ? 1 : 0);
    ushort* tr = (ushort*)rin; rin = rout; rout = tr;
  }
}